// Round 20
// baseline (584.463 us; speedup 1.0000x reference)
//
#include <hip/hip_runtime.h>
#include <hip/hip_fp16.h>

#define B_ 2
#define S_ 2048
#define HD_ 2048
#define NH_ 16
#define DH_ 128
#define L_ 512
#define WINDOW_ 128
#define SINKS_ 16
#define KTOP_ 64
#define KST 2052   /* keys[] row stride in u16 */

typedef __attribute__((ext_vector_type(4))) float f32x4;
typedef __attribute__((ext_vector_type(8))) __bf16 bf16x8;

__device__ inline unsigned short f2bf(float f) {
  unsigned int u = __float_as_uint(f);
  unsigned int r = (u + 0x7FFFu + ((u >> 16) & 1u)) >> 16;
  return (unsigned short)r;
}
__device__ inline float bf2f(unsigned short u) {
  unsigned int x = ((unsigned int)u) << 16;
  return __uint_as_float(x);
}
__device__ inline unsigned int mono(float f) {
  unsigned int u = __float_as_uint(f);
  return (u & 0x80000000u) ? ~u : (u | 0x80000000u);
}
// midpoint dequant of a 16-bit mono key back to float
__device__ inline float dq16(unsigned int k16) {
  unsigned int m = (k16 << 16) | 0x8000u;
  unsigned int u = (m & 0x80000000u) ? (m & 0x7fffffffu) : ~m;
  return __uint_as_float(u);
}
__device__ inline void gl16(const unsigned short* g, unsigned short* l) {
  __builtin_amdgcn_global_load_lds(
      (const __attribute__((address_space(1))) unsigned int*)g,
      (__attribute__((address_space(3))) unsigned int*)l, 16, 0, 0);
}

// ---------------- merged preprocessing: cast x + 5 weight transposes ----------------
__device__ inline void trans_cast_dev(const float* __restrict__ W,
                                      unsigned short* __restrict__ WT,
                                      int K, int N, int bx, int by, int t,
                                      unsigned short th[32][33]) {
  int n0 = bx * 32, k0 = by * 32;
  int cx = t & 31, ry = t >> 5;
#pragma unroll
  for (int it = 0; it < 4; ++it) {
    int kk = ry + it * 8;
    th[cx][kk] = f2bf(W[(size_t)(k0 + kk) * N + n0 + cx]);
  }
  __syncthreads();
#pragma unroll
  for (int it = 0; it < 4; ++it) {
    int nn = ry + it * 8;
    WT[(size_t)(n0 + nn) * K + k0 + cx] = th[nn][cx];
  }
}

__device__ inline void trans_split_dev(const float* __restrict__ W,
                                       unsigned short* __restrict__ WTh,
                                       unsigned short* __restrict__ WTl,
                                       int K, int N, int bx, int by, int t,
                                       unsigned short th[32][33],
                                       unsigned short tl[32][33]) {
  int n0 = bx * 32, k0 = by * 32;
  int cx = t & 31, ry = t >> 5;
#pragma unroll
  for (int it = 0; it < 4; ++it) {
    int kk = ry + it * 8;
    float v = W[(size_t)(k0 + kk) * N + n0 + cx];
    unsigned short h = f2bf(v);
    th[cx][kk] = h;
    tl[cx][kk] = f2bf(v - bf2f(h));
  }
  __syncthreads();
#pragma unroll
  for (int it = 0; it < 4; ++it) {
    int nn = ry + it * 8;
    WTh[(size_t)(n0 + nn) * K + k0 + cx] = th[nn][cx];
    WTl[(size_t)(n0 + nn) * K + k0 + cx] = tl[nn][cx];
  }
}

__global__ __launch_bounds__(256) void prep_all(const float* __restrict__ x,
                                                const float* __restrict__ Wq,
                                                const float* __restrict__ Wc,
                                                const float* __restrict__ Wk,
                                                const float* __restrict__ Wv,
                                                const float* __restrict__ Wo,
                                                unsigned short* __restrict__ x_bf,
                                                unsigned short* __restrict__ WqT,
                                                unsigned short* __restrict__ WcTh,
                                                unsigned short* __restrict__ WcTl,
                                                unsigned short* __restrict__ WkT,
                                                unsigned short* __restrict__ WvT,
                                                unsigned short* __restrict__ WoT) {
  __shared__ unsigned short th[32][33];
  __shared__ unsigned short tl[32][33];
  int bid = blockIdx.x;
  int t = threadIdx.x;
  if (bid < 2048) {
    const int n = 4096 * 2048;
    const int stride = 2048 * 256 * 4;
    for (int i = (bid * 256 + t) * 4; i < n; i += stride) {
      float4 v = *(const float4*)(x + i);
      ushort4 h;
      h.x = f2bf(v.x); h.y = f2bf(v.y); h.z = f2bf(v.z); h.w = f2bf(v.w);
      *(ushort4*)(x_bf + i) = h;
    }
  } else if (bid < 2048 + 4096) {
    int bb = bid - 2048;
    trans_cast_dev(Wq, WqT, 2048, 2048, bb & 63, bb >> 6, t, th);
  } else if (bid < 2048 + 4096 + 1024) {
    int bb = bid - (2048 + 4096);
    trans_split_dev(Wc, WcTh, WcTl, 2048, 512, bb & 15, bb >> 4, t, th, tl);
  } else if (bid < 2048 + 4096 + 2048) {
    int bb = bid - (2048 + 4096 + 1024);
    trans_cast_dev(Wk, WkT, 512, 2048, bb & 63, bb >> 6, t, th);
  } else if (bid < 2048 + 4096 + 3072) {
    int bb = bid - (2048 + 4096 + 2048);
    trans_cast_dev(Wv, WvT, 512, 2048, bb & 63, bb >> 6, t, th);
  } else {
    int bb = bid - (2048 + 4096 + 3072);
    trans_cast_dev(Wo, WoT, 2048, 2048, bb & 63, bb >> 6, t, th);
  }
}

// ---------------- 2-term GEMM, 64x128 tile: C = A * (Bth+Btl)^T, bf16 out ----------------
__global__ __launch_bounds__(256) void gemm_c64(const unsigned short* __restrict__ Ah,
                                                const unsigned short* __restrict__ Bth,
                                                const unsigned short* __restrict__ Btl,
                                                unsigned short* __restrict__ Chi,
                                                int M, int N, int K) {
  __shared__ unsigned short lAh[64 * 32];
  __shared__ unsigned short lBh[128 * 32];
  __shared__ unsigned short lBl[128 * 32];
  int t = threadIdx.x;
  int row0 = blockIdx.x * 64, col0 = blockIdx.y * 128;
  int w = t >> 6, lane = t & 63;
  int wm = w >> 1, wn = w & 1;
  int lr = lane & 15, g = lane >> 4;

  f32x4 acc[2][4] = {};

  for (int kt = 0; kt < K; kt += 32) {
    {
      int Lb = w * 1024;
      int L = Lb + lane * 16;
      int rr = L >> 6, kc = (L & 63) >> 1;
      size_t offA = (size_t)(row0 + rr) * K + kt + kc;
      gl16(Ah + offA, lAh + Lb / 2);
      int Lb0 = (2 * w) * 1024;
      int L0 = Lb0 + lane * 16;
      int rr0 = L0 >> 6, kc0 = (L0 & 63) >> 1;
      size_t offB0 = (size_t)(col0 + rr0) * K + kt + kc0;
      gl16(Bth + offB0, lBh + Lb0 / 2);
      gl16(Btl + offB0, lBl + Lb0 / 2);
      int Lb1 = (2 * w + 1) * 1024;
      int L1 = Lb1 + lane * 16;
      int rr1 = L1 >> 6, kc1 = (L1 & 63) >> 1;
      size_t offB1 = (size_t)(col0 + rr1) * K + kt + kc1;
      gl16(Bth + offB1, lBh + Lb1 / 2);
      gl16(Btl + offB1, lBl + Lb1 / 2);
    }
    __syncthreads();
    bf16x8 af[2], bgh[4], bgl[4];
#pragma unroll
    for (int m = 0; m < 2; ++m)
      af[m] = *(const bf16x8*)&lAh[(wm * 32 + m * 16 + lr) * 32 + g * 8];
#pragma unroll
    for (int n = 0; n < 4; ++n) {
      bgh[n] = *(const bf16x8*)&lBh[(wn * 64 + n * 16 + lr) * 32 + g * 8];
      bgl[n] = *(const bf16x8*)&lBl[(wn * 64 + n * 16 + lr) * 32 + g * 8];
    }
#pragma unroll
    for (int m = 0; m < 2; ++m)
#pragma unroll
      for (int n = 0; n < 4; ++n) {
        acc[m][n] = __builtin_amdgcn_mfma_f32_16x16x32_bf16(af[m], bgh[n], acc[m][n], 0, 0, 0);
        acc[m][n] = __builtin_amdgcn_mfma_f32_16x16x32_bf16(af[m], bgl[n], acc[m][n], 0, 0, 0);
      }
    __syncthreads();
  }

#pragma unroll
  for (int m = 0; m < 2; ++m)
#pragma unroll
    for (int n = 0; n < 4; ++n)
#pragma unroll
      for (int r2 = 0; r2 < 4; ++r2) {
        int row = row0 + wm * 32 + m * 16 + g * 4 + r2;
        int col = col0 + wn * 64 + n * 16 + lr;
        Chi[(size_t)row * N + col] = f2bf(acc[m][n][r2]);
      }
}

// ---------------- 1-term bf16 MFMA GEMM: C = Ah * Bth^T (bf16 out, scale) ----------------
__global__ __launch_bounds__(256) void gemm_1term(const unsigned short* __restrict__ Ah,
                                                  const unsigned short* __restrict__ Bth,
                                                  unsigned short* __restrict__ Chi,
                                                  int M, int N, int K, float oscale) {
  __shared__ unsigned short lA[128 * 32];
  __shared__ unsigned short lB[128 * 32];
  int t = threadIdx.x;
  int row0 = blockIdx.x * 128, col0 = blockIdx.y * 128;
  int w = t >> 6, lane = t & 63;
  int wm = w >> 1, wn = w & 1;
  int lr = lane & 15, g = lane >> 4;

  f32x4 acc[4][4] = {};

  for (int kt = 0; kt < K; kt += 32) {
#pragma unroll
    for (int cc = 0; cc < 2; ++cc) {
      int chunk = cc * 4 + w;
      int Lb = chunk * 1024;
      int L = Lb + lane * 16;
      int rr = L >> 6;
      int kc = (L & 63) >> 1;
      size_t offA = (size_t)(row0 + rr) * K + kt + kc;
      size_t offB = (size_t)(col0 + rr) * K + kt + kc;
      gl16(Ah + offA, lA + Lb / 2);
      gl16(Bth + offB, lB + Lb / 2);
    }
    __syncthreads();
    bf16x8 af[4], bg[4];
#pragma unroll
    for (int m = 0; m < 4; ++m) af[m] = *(const bf16x8*)&lA[(wm * 64 + m * 16 + lr) * 32 + g * 8];
#pragma unroll
    for (int n = 0; n < 4; ++n) bg[n] = *(const bf16x8*)&lB[(wn * 64 + n * 16 + lr) * 32 + g * 8];
#pragma unroll
    for (int m = 0; m < 4; ++m)
#pragma unroll
      for (int n = 0; n < 4; ++n)
        acc[m][n] = __builtin_amdgcn_mfma_f32_16x16x32_bf16(af[m], bg[n], acc[m][n], 0, 0, 0);
    __syncthreads();
  }

#pragma unroll
  for (int m = 0; m < 4; ++m)
#pragma unroll
    for (int n = 0; n < 4; ++n)
#pragma unroll
      for (int r2 = 0; r2 < 4; ++r2) {
        int row = row0 + wm * 64 + m * 16 + g * 4 + r2;
        int col = col0 + wn * 64 + n * 16 + lr;
        Chi[(size_t)row * N + col] = f2bf(acc[m][n][r2] * oscale);
      }
}

// ---------------- 1-term bf16 MFMA GEMM, f16 out (for V) ----------------
__global__ __launch_bounds__(256) void gemm_1h(const unsigned short* __restrict__ Ah,
                                               const unsigned short* __restrict__ Bth,
                                               unsigned short* __restrict__ Ch,
                                               int M, int N, int K) {
  __shared__ unsigned short lA[128 * 32];
  __shared__ unsigned short lB[128 * 32];
  int t = threadIdx.x;
  int row0 = blockIdx.x * 128, col0 = blockIdx.y * 128;
  int w = t >> 6, lane = t & 63;
  int wm = w >> 1, wn = w & 1;
  int lr = lane & 15, g = lane >> 4;

  f32x4 acc[4][4] = {};

  for (int kt = 0; kt < K; kt += 32) {
#pragma unroll
    for (int cc = 0; cc < 2; ++cc) {
      int chunk = cc * 4 + w;
      int Lb = chunk * 1024;
      int L = Lb + lane * 16;
      int rr = L >> 6;
      int kc = (L & 63) >> 1;
      size_t offA = (size_t)(row0 + rr) * K + kt + kc;
      size_t offB = (size_t)(col0 + rr) * K + kt + kc;
      gl16(Ah + offA, lA + Lb / 2);
      gl16(Bth + offB, lB + Lb / 2);
    }
    __syncthreads();
    bf16x8 af[4], bg[4];
#pragma unroll
    for (int m = 0; m < 4; ++m) af[m] = *(const bf16x8*)&lA[(wm * 64 + m * 16 + lr) * 32 + g * 8];
#pragma unroll
    for (int n = 0; n < 4; ++n) bg[n] = *(const bf16x8*)&lB[(wn * 64 + n * 16 + lr) * 32 + g * 8];
#pragma unroll
    for (int m = 0; m < 4; ++m)
#pragma unroll
      for (int n = 0; n < 4; ++n)
        acc[m][n] = __builtin_amdgcn_mfma_f32_16x16x32_bf16(af[m], bg[n], acc[m][n], 0, 0, 0);
    __syncthreads();
  }

#pragma unroll
  for (int m = 0; m < 4; ++m)
#pragma unroll
    for (int n = 0; n < 4; ++n)
#pragma unroll
      for (int r2 = 0; r2 < 4; ++r2) {
        int row = row0 + wm * 64 + m * 16 + g * 4 + r2;
        int col = col0 + wn * 64 + n * 16 + lr;
        __half hv = __float2half(acc[m][n][r2]);
        Ch[(size_t)row * N + col] = __half_as_ushort(hv);
      }
}

// ---------------- 1-term bf16 MFMA GEMM: Cf = Ah * Bth^T (f32 out) ----------------
__global__ __launch_bounds__(256) void gemm_1f(const unsigned short* __restrict__ Ah,
                                               const unsigned short* __restrict__ Bth,
                                               float* __restrict__ Cf,
                                               int M, int N, int K) {
  __shared__ unsigned short lA[128 * 32];
  __shared__ unsigned short lB[128 * 32];
  int t = threadIdx.x;
  int row0 = blockIdx.x * 128, col0 = blockIdx.y * 128;
  int w = t >> 6, lane = t & 63;
  int wm = w >> 1, wn = w & 1;
  int lr = lane & 15, g = lane >> 4;

  f32x4 acc[4][4] = {};

  for (int kt = 0; kt < K; kt += 32) {
#pragma unroll
    for (int cc = 0; cc < 2; ++cc) {
      int chunk = cc * 4 + w;
      int Lb = chunk * 1024;
      int L = Lb + lane * 16;
      int rr = L >> 6;
      int kc = (L & 63) >> 1;
      size_t offA = (size_t)(row0 + rr) * K + kt + kc;
      size_t offB = (size_t)(col0 + rr) * K + kt + kc;
      gl16(Ah + offA, lA + Lb / 2);
      gl16(Bth + offB, lB + Lb / 2);
    }
    __syncthreads();
    bf16x8 af[4], bg[4];
#pragma unroll
    for (int m = 0; m < 4; ++m) af[m] = *(const bf16x8*)&lA[(wm * 64 + m * 16 + lr) * 32 + g * 8];
#pragma unroll
    for (int n = 0; n < 4; ++n) bg[n] = *(const bf16x8*)&lB[(wn * 64 + n * 16 + lr) * 32 + g * 8];
#pragma unroll
    for (int m = 0; m < 4; ++m)
#pragma unroll
      for (int n = 0; n < 4; ++n)
        acc[m][n] = __builtin_amdgcn_mfma_f32_16x16x32_bf16(af[m], bg[n], acc[m][n], 0, 0, 0);
    __syncthreads();
  }

#pragma unroll
  for (int m = 0; m < 4; ++m)
#pragma unroll
    for (int n = 0; n < 4; ++n)
#pragma unroll
      for (int r2 = 0; r2 < 4; ++r2) {
        int row = row0 + wm * 64 + m * 16 + g * 4 + r2;
        int col = col0 + wn * 64 + n * 16 + lr;
        Cf[(size_t)row * N + col] = acc[m][n][r2];
      }
}

// ---------------- fused attention: QK^T -> u16 keys -> select -> PV (f16) ----------------
// One block = (b, h, 16 query rows). 1024 threads = 16 waves; one row per wave after A.
// Marking stores (j<<16 | k16); exp deferred; PV: aligned ds_read_b128 + 4-deep gather.
__global__ __launch_bounds__(1024, 8) void attn_fused(const unsigned short* __restrict__ qh,
                                                      const unsigned short* __restrict__ kh,
                                                      const unsigned short* __restrict__ vhf,
                                                      const int* __restrict__ forget,
                                                      unsigned short* __restrict__ oh) {
  __shared__ unsigned short keys[16][KST];    // 65.7 KB: mono(score)>>16
  __shared__ unsigned int scratch[16][224];   // 14.3 KB: hist then packed lists

  int bid = blockIdx.x;
  int bh = bid >> 7;
  int tile = 127 - (bid & 127);               // big tiles dispatched first
  int b = bh >> 4, h = bh & 15;
  int i0 = tile * 16;
  int t = threadIdx.x;
  int w = t >> 6, lane = t & 63;
  int lr = lane & 15, g = lane >> 4;

  scratch[w][lane] = 0;
  scratch[w][lane + 64] = 0;
  __syncthreads();

  // ---- Phase A: QK^T (1-term bf16) + fused pass-0 histogram ----
  size_t qbase = ((size_t)(b * S_ + i0 + lr)) * HD_ + h * DH_;
  bf16x8 aq[4];
#pragma unroll
  for (int ks = 0; ks < 4; ++ks) aq[ks] = *(const bf16x8*)(qh + qbase + ks * 32 + g * 8);

  for (int kblk = w; kblk <= tile; kblk += 16) {
    int j0 = kblk * 16;
    size_t kbase = ((size_t)(b * S_ + j0 + lr)) * HD_ + h * DH_;
    f32x4 acc = {0.f, 0.f, 0.f, 0.f};
#pragma unroll
    for (int ks = 0; ks < 4; ++ks) {
      bf16x8 bk = *(const bf16x8*)(kh + kbase + ks * 32 + g * 8);
      acc = __builtin_amdgcn_mfma_f32_16x16x32_bf16(aq[ks], bk, acc, 0, 0, 0);
    }
    int j = j0 + lr;
#pragma unroll
    for (int r2 = 0; r2 < 4; ++r2) {
      int rr = g * 4 + r2;
      unsigned int k16 = mono(acc[r2]) >> 16;
      keys[rr][j] = (unsigned short)k16;
      int irow = i0 + rr;
      if (j >= SINKS_ && j <= irow - WINDOW_) {
        unsigned int bkt = k16 >> 8;
        atomicAdd(&scratch[rr][bkt >> 1], 1u << ((bkt & 1u) * 16));
      }
    }
  }
  __syncthreads();

  // ---- Phase B: wave-private row select on u16 keys ----
  int r = w;
  int i = i0 + r;
  size_t rsg = (size_t)bh * S_ + i;

  int hi = i - WINDOW_;
  int C = hi - SINKS_ + 1;
  int mode = (C <= 0) ? 0 : (C <= KTOP_ ? 1 : 2);
  unsigned int T16 = 0; int neq = 0;

  if (mode == 2) {
    int cmax = hi >> 6;
    unsigned int need = KTOP_;
    unsigned int d0_, d1_;
    // pass 0: reduce the histogram Phase A already built
    {
      unsigned int w0 = scratch[r][lane * 2], w1 = scratch[r][lane * 2 + 1];
      unsigned int s0 = (w0 & 0xffffu) + (w0 >> 16) + (w1 & 0xffffu) + (w1 >> 16);
      unsigned int suf = s0;
#pragma unroll
      for (int off = 1; off < 64; off <<= 1) {
        unsigned int vv = __shfl_down(suf, off);
        if (lane + off < 64) suf += vv;
      }
      unsigned int sufn = __shfl_down(suf, 1);
      if (lane == 63) sufn = 0;
      bool pl = (suf >= need) && (sufn < need);
      unsigned long long bal = __ballot(pl);
      int gg = __ffsll(bal) - 1;
      unsigned int basec = __shfl(sufn, gg);
      unsigned int cum = basec; int dstar = 4 * gg;
#pragma unroll
      for (int dd = 3; dd >= 0; --dd) {
        int d = 4 * gg + dd;
        unsigned int hd = (scratch[r][d >> 1] >> ((d & 1) * 16)) & 0xffffu;
        cum += hd;
        if (cum >= need) { dstar = d; break; }
      }
      unsigned int hstar = (scratch[r][dstar >> 1] >> ((dstar & 1) * 16)) & 0xffffu;
      need -= (cum - hstar);
      d0_ = (unsigned int)dstar;
    }
    // pass 1: low 8 bits among keys with high byte == d0_
    scratch[r][lane] = 0; scratch[r][lane + 64] = 0;
    for (int c = 0; c <= cmax; ++c) {
      int j = c * 64 + lane;
      unsigned int key = keys[r][j];
      bool cand = (j >= SINKS_) && (j <= hi);
      if (cand && (key >> 8) == d0_) {
        unsigned int bkt = key & 255u;
        atomicAdd(&scratch[r][bkt >> 1], 1u << ((bkt & 1u) * 16));
      }
    }
    {
      unsigned int w0 = scratch[r][lane * 2], w1 = scratch[r][lane * 2 + 1];
      unsigned int s0 = (w0 & 0xffffu) + (w0 >> 16) + (w1 & 0xffffu) + (w1 >> 16);
      unsigned int suf = s0;
#pragma unroll
      for (int off = 1; off < 64; off <<= 1) {
        unsigned int vv = __shfl_down(suf, off);
        if (lane + off < 64) suf += vv;
      }
      unsigned int sufn = __shfl_down(suf, 1);
      if (lane == 63) sufn = 0;
      bool pl = (suf >= need) && (sufn < need);
      unsigned long long bal = __ballot(pl);
      int gg = __ffsll(bal) - 1;
      unsigned int basec = __shfl(sufn, gg);
      unsigned int cum = basec; int dstar = 4 * gg;
#pragma unroll
      for (int dd = 3; dd >= 0; --dd) {
        int d = 4 * gg + dd;
        unsigned int hd = (scratch[r][d >> 1] >> ((d & 1) * 16)) & 0xffffu;
        cum += hd;
        if (cum >= need) { dstar = d; break; }
      }
      unsigned int hstar = (scratch[r][dstar >> 1] >> ((dstar & 1) * 16)) & 0xffffu;
      need -= (cum - hstar);
      d1_ = (unsigned int)dstar;
    }
    T16 = (d0_ << 8) | d1_;
    neq = (int)need;
  }

  // marking + compaction (region-split; stores j<<16|k16; ties ascending)
  int neq_run = neq;
  int cnt = 0;
  int nch = i >> 6;
  int cfull_end = (mode == 2) ? ((hi + 1) >> 6) : 0;
  for (int c = 0; c <= nch; ++c) {
    int j = c * 64 + lane;
    unsigned int k16v = keys[r][j];
    if (mode != 2 || c * 64 > hi) {
      bool allowed = j <= i;
      unsigned long long am = __ballot(allowed);
      if (allowed) {
        int pos = cnt + __popcll(am & ((1ull << lane) - 1ull));
        scratch[r][pos] = ((unsigned int)j << 16) | k16v;
      }
      cnt += __popcll(am);
    } else if (c >= 1 && c < cfull_end) {
      bool sel = k16v > T16;
      bool iseq = (k16v == T16);
      unsigned long long em = __ballot(iseq);
      if (iseq) {
        int rk = __popcll(em & ((1ull << lane) - 1ull));
        if (rk < neq_run) sel = true;
      }
      int taken = __popcll(em);
      neq_run -= (taken < neq_run) ? taken : neq_run;
      unsigned long long am = __ballot(sel);
      if (sel) {
        int pos = cnt + __popcll(am & ((1ull << lane) - 1ull));
        scratch[r][pos] = ((unsigned int)j << 16) | k16v;
      }
      cnt += __popcll(am);
    } else {
      bool valid = j <= i;
      bool isbase = valid && ((j < SINKS_) || ((i - j) < WINDOW_));
      bool iscand = valid && !isbase;
      bool sel = false, iseq = false;
      if (iscand) {
        sel = k16v > T16;
        iseq = (k16v == T16);
      }
      unsigned long long em = __ballot(iseq);
      if (iseq) {
        int rk = __popcll(em & ((1ull << lane) - 1ull));
        if (rk < neq_run) sel = true;
      }
      int taken = __popcll(em);
      neq_run -= (taken < neq_run) ? taken : neq_run;
      bool allowed = isbase || sel;
      unsigned long long am = __ballot(allowed);
      if (allowed) {
        int pos = cnt + __popcll(am & ((1ull << lane) - 1ull));
        scratch[r][pos] = ((unsigned int)j << 16) | k16v;
      }
      cnt += __popcll(am);
    }
  }

  // forget pass: scattered global reads ONLY for selected candidates; recompact.
  {
    const int* frow = forget + rsg * (size_t)S_;
    int newcnt = 0;
    for (int c0 = 0; c0 < cnt; c0 += 64) {
      int p = c0 + lane;
      bool active = p < cnt;
      unsigned int pk = active ? scratch[r][p] : 0u;
      int j = (int)(pk >> 16);
      bool isb = (j < SINKS_) || ((i - j) < WINDOW_);
      bool fbit = false;
      if (active && !isb) fbit = (frow[j] != 0);
      bool keep = active && !fbit;
      unsigned long long km = __ballot(keep);
      if (keep) {
        int npos = newcnt + __popcll(km & ((1ull << lane) - 1ull));
        scratch[r][npos] = pk;
      }
      newcnt += __popcll(km);
    }
    cnt = newcnt;
  }

  // weights over the compact list: w = exp(dq(key)); overwrite low half with f16 w
  float sum = 0.f;
  for (int p = lane; p < cnt; p += 64) {
    unsigned int pk = scratch[r][p];
    float wgt = __expf(dq16(pk & 0xffffu));
    sum += wgt;
    scratch[r][p] = (pk & 0xffff0000u) |
                    (unsigned int)__half_as_ushort(__float2half(wgt));
  }
#pragma unroll
  for (int off = 32; off >= 1; off >>= 1) sum += __shfl_xor(sum, off);
  float inv = 1.0f / sum;

  // ---- Phase C: PV in packed f16. 16 lanes x 8 dims; 4-aligned quarter slices ----
  int quarter = lane >> 4;
  int q16 = lane & 15;
  int d0 = q16 * 8;
  int qs = (((cnt + 3) >> 2) + 3) & ~3;       // 4-aligned quarter stride
  int p0 = quarter * qs;
  int p1 = p0 + qs; if (p1 > cnt) p1 = cnt;
  size_t vb0 = ((size_t)(b * S_)) * HD_ + h * DH_ + d0;

  __half2 A0 = __floats2half2_rn(0.f, 0.f);
  __half2 A1 = A0, A2 = A0, A3 = A0;
  __builtin_amdgcn_s_setprio(1);
  int p = p0;
  for (; p + 4 <= p1; p += 4) {
    uint4 pks = *(const uint4*)&scratch[r][p];   // 16B-aligned ds_read_b128
    int j0q = (int)(pks.x >> 16), j1q = (int)(pks.y >> 16);
    int j2q = (int)(pks.z >> 16), j3q = (int)(pks.w >> 16);
    uint4 v0 = *(const uint4*)(vhf + vb0 + (size_t)j0q * HD_);
    uint4 v1 = *(const uint4*)(vhf + vb0 + (size_t)j1q * HD_);
    uint4 v2 = *(const uint4*)(vhf + vb0 + (size_t)j2q * HD_);
    uint4 v3 = *(const uint4*)(vhf + vb0 + (size_t)j3q * HD_);
    __half2 w0 = __half2half2(__ushort_as_half((unsigned short)(pks.x & 0xffffu)));
    __half2 w1 = __half2half2(__ushort_as_half((unsigned short)(pks.y & 0xffffu)));
    __half2 w2 = __half2half2(__ushort_as_half((unsigned short)(pks.z & 0xffffu)));
    __half2 w3 = __half2half2(__ushort_as_half((unsigned short)(pks.w & 0xffffu)));
    A0 = __hfma2(w0, *(const __half2*)&v0.x, A0);
    A1 = __hfma2(w0, *(const __half2*)&v0.y, A1);
    A2 = __hfma2(w0, *(const __half2*)&v0.z, A2);
    A3 = __hfma2(w0, *(const __half2*)&v0.w, A3);
    A0 = __hfma2(w1, *(const __half2*)&v1.x, A0);
    A1 = __hfma2(w1, *(const __half2*)&v1.y, A1);
    A2 = __hfma2(w1, *(const __half2*)&v1.z, A2);
    A3 = __hfma2(w1, *(const __half2*)&v1.w, A3);
    A0 = __hfma2(w2, *(const __half2*)&v2.x, A0);
    A1 = __hfma2(w2, *(const __half2*)&v2.y, A1);
    A2 = __hfma2(w2, *(const __half2*)&v2.z, A2);
    A3 = __hfma2(w2, *(const __half2*)&v2.w, A3);
    A0 = __hfma2(w3, *(const __half2*)&v3.x, A0);
    A1 = __hfma2(w3, *(const __half2*)&v3.y, A1);
    A2 = __hfma2(w3, *(const __half2*)&v3.z, A2);
    A3 = __hfma2(w3, *(const __half2*)&v3.w, A3);
  }
  for (; p < p1; ++p) {
    unsigned int pk = scratch[r][p];
    int j = (int)(pk >> 16);
    __half2 w2 = __half2half2(__ushort_as_half((unsigned short)(pk & 0xffffu)));
    uint4 vj = *(const uint4*)(vhf + vb0 + (size_t)j * HD_);
    A0 = __hfma2(w2, *(const __half2*)&vj.x, A0);
    A1 = __hfma2(w2, *(const __half2*)&vj.y, A1);
    A2 = __hfma2(w2, *(const __half2*)&vj.z, A2);
    A3 = __hfma2(w2, *(const __half2*)&vj.w, A3);
  }
  __builtin_amdgcn_s_setprio(0);
#pragma unroll
  for (int off = 16; off <= 32; off <<= 1) {
    int v0 = __shfl_xor(*(int*)&A0, off);
    int v1 = __shfl_xor(*(int*)&A1, off);
    int v2 = __shfl_xor(*(int*)&A2, off);
    int v3 = __shfl_xor(*(int*)&A3, off);
    A0 = __hadd2(A0, *(__half2*)&v0);
    A1 = __hadd2(A1, *(__half2*)&v1);
    A2 = __hadd2(A2, *(__half2*)&v2);
    A3 = __hadd2(A3, *(__half2*)&v3);
  }
  if (quarter == 0) {
    float2 f0 = __half22float2(A0), f1 = __half22float2(A1);
    float2 f2 = __half22float2(A2), f3 = __half22float2(A3);
    ushort4 h0, h1;
    h0.x = f2bf(f0.x * inv); h0.y = f2bf(f0.y * inv);
    h0.z = f2bf(f1.x * inv); h0.w = f2bf(f1.y * inv);
    h1.x = f2bf(f2.x * inv); h1.y = f2bf(f2.y * inv);
    h1.z = f2bf(f3.x * inv); h1.w = f2bf(f3.y * inv);
    size_t oidx = ((size_t)(b * S_ + i)) * HD_ + h * DH_ + d0;
    *(ushort4*)(oh + oidx) = h0;
    *(ushort4*)(oh + oidx + 4) = h1;
  }
}

extern "C" void kernel_launch(void* const* d_in, const int* in_sizes, int n_in,
                              void* d_out, int out_size, void* d_ws, size_t ws_size,
                              hipStream_t stream) {
  (void)in_sizes; (void)n_in; (void)out_size; (void)ws_size;
  const float* x  = (const float*)d_in[0];
  const float* Wq = (const float*)d_in[1];
  const float* Wc = (const float*)d_in[2];
  const float* Wk = (const float*)d_in[3];
  const float* Wv = (const float*)d_in[4];
  const float* Wo = (const float*)d_in[5];
  const int* forget = (const int*)d_in[6];  // bool widened to int32 (verified r3)

  char* ws = (char*)d_ws;
  size_t off = 0;
  auto alloc = [&](size_t bytes) { char* p = ws + off; off += (bytes + 255) & ~(size_t)255; return p; };

  unsigned short* x_bf = (unsigned short*)alloc((size_t)4096 * 2048 * 2);  // reused as o
  unsigned short* WqT  = (unsigned short*)alloc((size_t)2048 * 2048 * 2);
  unsigned short* WcTh = (unsigned short*)alloc((size_t)512 * 2048 * 2);
  unsigned short* WcTl = (unsigned short*)alloc((size_t)512 * 2048 * 2);
  unsigned short* WkT  = (unsigned short*)alloc((size_t)2048 * 512 * 2);
  unsigned short* WvT  = (unsigned short*)alloc((size_t)2048 * 512 * 2);
  unsigned short* WoT  = (unsigned short*)alloc((size_t)2048 * 2048 * 2);
  unsigned short* q_hi = (unsigned short*)alloc((size_t)4096 * 2048 * 2);
  unsigned short* c_hi = (unsigned short*)alloc((size_t)4096 * 512 * 2);
  unsigned short* k_hi = (unsigned short*)alloc((size_t)4096 * 2048 * 2);
  unsigned short* v_hf = (unsigned short*)alloc((size_t)4096 * 2048 * 2);

  unsigned short* o_hi = x_bf;

  const float scale = 0.08838834764831845f;

  prep_all<<<13312, 256, 0, stream>>>(x, Wq, Wc, Wk, Wv, Wo,
                                      x_bf, WqT, WcTh, WcTl, WkT, WvT, WoT);

  gemm_c64<<<dim3(64, 4), 256, 0, stream>>>(x_bf, WcTh, WcTl, c_hi, 4096, 512, 2048);
  gemm_1term<<<dim3(32, 16), 256, 0, stream>>>(x_bf, WqT, q_hi, 4096, 2048, 2048, scale);
  gemm_1term<<<dim3(32, 16), 256, 0, stream>>>(c_hi, WkT, k_hi, 4096, 2048, 512, 1.0f);
  gemm_1h<<<dim3(32, 16), 256, 0, stream>>>(c_hi, WvT, v_hf, 4096, 2048, 512);

  attn_fused<<<4096, 1024, 0, stream>>>(q_hi, k_hi, v_hf, forget, o_hi);

  gemm_1f<<<dim3(32, 16), 256, 0, stream>>>(o_hi, WoT, (float*)d_out, 4096, 2048, 2048);
}

// Round 21
// 572.849 us; speedup vs baseline: 1.0203x; 1.0203x over previous
//
#include <hip/hip_runtime.h>
#include <hip/hip_fp16.h>

#define B_ 2
#define S_ 2048
#define HD_ 2048
#define NH_ 16
#define DH_ 128
#define L_ 512
#define WINDOW_ 128
#define SINKS_ 16
#define KTOP_ 64
#define KST 2052   /* keys[] row stride in u16 */

typedef __attribute__((ext_vector_type(4))) float f32x4;
typedef __attribute__((ext_vector_type(8))) __bf16 bf16x8;

__device__ inline unsigned short f2bf(float f) {
  unsigned int u = __float_as_uint(f);
  unsigned int r = (u + 0x7FFFu + ((u >> 16) & 1u)) >> 16;
  return (unsigned short)r;
}
__device__ inline float bf2f(unsigned short u) {
  unsigned int x = ((unsigned int)u) << 16;
  return __uint_as_float(x);
}
__device__ inline unsigned int mono(float f) {
  unsigned int u = __float_as_uint(f);
  return (u & 0x80000000u) ? ~u : (u | 0x80000000u);
}
// midpoint dequant of a 16-bit mono key back to float
__device__ inline float dq16(unsigned int k16) {
  unsigned int m = (k16 << 16) | 0x8000u;
  unsigned int u = (m & 0x80000000u) ? (m & 0x7fffffffu) : ~m;
  return __uint_as_float(u);
}
__device__ inline void gl16(const unsigned short* g, unsigned short* l) {
  __builtin_amdgcn_global_load_lds(
      (const __attribute__((address_space(1))) unsigned int*)g,
      (__attribute__((address_space(3))) unsigned int*)l, 16, 0, 0);
}

// ---------------- merged preprocessing: cast x + 5 weight transposes ----------------
__device__ inline void trans_cast_dev(const float* __restrict__ W,
                                      unsigned short* __restrict__ WT,
                                      int K, int N, int bx, int by, int t,
                                      unsigned short th[32][33]) {
  int n0 = bx * 32, k0 = by * 32;
  int cx = t & 31, ry = t >> 5;
#pragma unroll
  for (int it = 0; it < 4; ++it) {
    int kk = ry + it * 8;
    th[cx][kk] = f2bf(W[(size_t)(k0 + kk) * N + n0 + cx]);
  }
  __syncthreads();
#pragma unroll
  for (int it = 0; it < 4; ++it) {
    int nn = ry + it * 8;
    WT[(size_t)(n0 + nn) * K + k0 + cx] = th[nn][cx];
  }
}

__device__ inline void trans_split_dev(const float* __restrict__ W,
                                       unsigned short* __restrict__ WTh,
                                       unsigned short* __restrict__ WTl,
                                       int K, int N, int bx, int by, int t,
                                       unsigned short th[32][33],
                                       unsigned short tl[32][33]) {
  int n0 = bx * 32, k0 = by * 32;
  int cx = t & 31, ry = t >> 5;
#pragma unroll
  for (int it = 0; it < 4; ++it) {
    int kk = ry + it * 8;
    float v = W[(size_t)(k0 + kk) * N + n0 + cx];
    unsigned short h = f2bf(v);
    th[cx][kk] = h;
    tl[cx][kk] = f2bf(v - bf2f(h));
  }
  __syncthreads();
#pragma unroll
  for (int it = 0; it < 4; ++it) {
    int nn = ry + it * 8;
    WTh[(size_t)(n0 + nn) * K + k0 + cx] = th[nn][cx];
    WTl[(size_t)(n0 + nn) * K + k0 + cx] = tl[nn][cx];
  }
}

__global__ __launch_bounds__(256) void prep_all(const float* __restrict__ x,
                                                const float* __restrict__ Wq,
                                                const float* __restrict__ Wc,
                                                const float* __restrict__ Wk,
                                                const float* __restrict__ Wv,
                                                const float* __restrict__ Wo,
                                                unsigned short* __restrict__ x_bf,
                                                unsigned short* __restrict__ WqT,
                                                unsigned short* __restrict__ WcTh,
                                                unsigned short* __restrict__ WcTl,
                                                unsigned short* __restrict__ WkT,
                                                unsigned short* __restrict__ WvT,
                                                unsigned short* __restrict__ WoT) {
  __shared__ unsigned short th[32][33];
  __shared__ unsigned short tl[32][33];
  int bid = blockIdx.x;
  int t = threadIdx.x;
  if (bid < 2048) {
    const int n = 4096 * 2048;
    const int stride = 2048 * 256 * 4;
    for (int i = (bid * 256 + t) * 4; i < n; i += stride) {
      float4 v = *(const float4*)(x + i);
      ushort4 h;
      h.x = f2bf(v.x); h.y = f2bf(v.y); h.z = f2bf(v.z); h.w = f2bf(v.w);
      *(ushort4*)(x_bf + i) = h;
    }
  } else if (bid < 2048 + 4096) {
    int bb = bid - 2048;
    trans_cast_dev(Wq, WqT, 2048, 2048, bb & 63, bb >> 6, t, th);
  } else if (bid < 2048 + 4096 + 1024) {
    int bb = bid - (2048 + 4096);
    trans_split_dev(Wc, WcTh, WcTl, 2048, 512, bb & 15, bb >> 4, t, th, tl);
  } else if (bid < 2048 + 4096 + 2048) {
    int bb = bid - (2048 + 4096 + 1024);
    trans_cast_dev(Wk, WkT, 512, 2048, bb & 63, bb >> 6, t, th);
  } else if (bid < 2048 + 4096 + 3072) {
    int bb = bid - (2048 + 4096 + 2048);
    trans_cast_dev(Wv, WvT, 512, 2048, bb & 63, bb >> 6, t, th);
  } else {
    int bb = bid - (2048 + 4096 + 3072);
    trans_cast_dev(Wo, WoT, 2048, 2048, bb & 63, bb >> 6, t, th);
  }
}

// ---------------- 2-term GEMM, 64x128 tile: C = A * (Bth+Btl)^T, bf16 out ----------------
__global__ __launch_bounds__(256) void gemm_c64(const unsigned short* __restrict__ Ah,
                                                const unsigned short* __restrict__ Bth,
                                                const unsigned short* __restrict__ Btl,
                                                unsigned short* __restrict__ Chi,
                                                int M, int N, int K) {
  __shared__ unsigned short lAh[64 * 32];
  __shared__ unsigned short lBh[128 * 32];
  __shared__ unsigned short lBl[128 * 32];
  int t = threadIdx.x;
  int row0 = blockIdx.x * 64, col0 = blockIdx.y * 128;
  int w = t >> 6, lane = t & 63;
  int wm = w >> 1, wn = w & 1;
  int lr = lane & 15, g = lane >> 4;

  f32x4 acc[2][4] = {};

  for (int kt = 0; kt < K; kt += 32) {
    {
      int Lb = w * 1024;
      int L = Lb + lane * 16;
      int rr = L >> 6, kc = (L & 63) >> 1;
      size_t offA = (size_t)(row0 + rr) * K + kt + kc;
      gl16(Ah + offA, lAh + Lb / 2);
      int Lb0 = (2 * w) * 1024;
      int L0 = Lb0 + lane * 16;
      int rr0 = L0 >> 6, kc0 = (L0 & 63) >> 1;
      size_t offB0 = (size_t)(col0 + rr0) * K + kt + kc0;
      gl16(Bth + offB0, lBh + Lb0 / 2);
      gl16(Btl + offB0, lBl + Lb0 / 2);
      int Lb1 = (2 * w + 1) * 1024;
      int L1 = Lb1 + lane * 16;
      int rr1 = L1 >> 6, kc1 = (L1 & 63) >> 1;
      size_t offB1 = (size_t)(col0 + rr1) * K + kt + kc1;
      gl16(Bth + offB1, lBh + Lb1 / 2);
      gl16(Btl + offB1, lBl + Lb1 / 2);
    }
    __syncthreads();
    bf16x8 af[2], bgh[4], bgl[4];
#pragma unroll
    for (int m = 0; m < 2; ++m)
      af[m] = *(const bf16x8*)&lAh[(wm * 32 + m * 16 + lr) * 32 + g * 8];
#pragma unroll
    for (int n = 0; n < 4; ++n) {
      bgh[n] = *(const bf16x8*)&lBh[(wn * 64 + n * 16 + lr) * 32 + g * 8];
      bgl[n] = *(const bf16x8*)&lBl[(wn * 64 + n * 16 + lr) * 32 + g * 8];
    }
#pragma unroll
    for (int m = 0; m < 2; ++m)
#pragma unroll
      for (int n = 0; n < 4; ++n) {
        acc[m][n] = __builtin_amdgcn_mfma_f32_16x16x32_bf16(af[m], bgh[n], acc[m][n], 0, 0, 0);
        acc[m][n] = __builtin_amdgcn_mfma_f32_16x16x32_bf16(af[m], bgl[n], acc[m][n], 0, 0, 0);
      }
    __syncthreads();
  }

#pragma unroll
  for (int m = 0; m < 2; ++m)
#pragma unroll
    for (int n = 0; n < 4; ++n)
#pragma unroll
      for (int r2 = 0; r2 < 4; ++r2) {
        int row = row0 + wm * 32 + m * 16 + g * 4 + r2;
        int col = col0 + wn * 64 + n * 16 + lr;
        Chi[(size_t)row * N + col] = f2bf(acc[m][n][r2]);
      }
}

// ---------------- 1-term bf16 MFMA GEMM: C = Ah * Bth^T (bf16 out, scale) ----------------
__global__ __launch_bounds__(256) void gemm_1term(const unsigned short* __restrict__ Ah,
                                                  const unsigned short* __restrict__ Bth,
                                                  unsigned short* __restrict__ Chi,
                                                  int M, int N, int K, float oscale) {
  __shared__ unsigned short lA[128 * 32];
  __shared__ unsigned short lB[128 * 32];
  int t = threadIdx.x;
  int row0 = blockIdx.x * 128, col0 = blockIdx.y * 128;
  int w = t >> 6, lane = t & 63;
  int wm = w >> 1, wn = w & 1;
  int lr = lane & 15, g = lane >> 4;

  f32x4 acc[4][4] = {};

  for (int kt = 0; kt < K; kt += 32) {
#pragma unroll
    for (int cc = 0; cc < 2; ++cc) {
      int chunk = cc * 4 + w;
      int Lb = chunk * 1024;
      int L = Lb + lane * 16;
      int rr = L >> 6;
      int kc = (L & 63) >> 1;
      size_t offA = (size_t)(row0 + rr) * K + kt + kc;
      size_t offB = (size_t)(col0 + rr) * K + kt + kc;
      gl16(Ah + offA, lA + Lb / 2);
      gl16(Bth + offB, lB + Lb / 2);
    }
    __syncthreads();
    bf16x8 af[4], bg[4];
#pragma unroll
    for (int m = 0; m < 4; ++m) af[m] = *(const bf16x8*)&lA[(wm * 64 + m * 16 + lr) * 32 + g * 8];
#pragma unroll
    for (int n = 0; n < 4; ++n) bg[n] = *(const bf16x8*)&lB[(wn * 64 + n * 16 + lr) * 32 + g * 8];
#pragma unroll
    for (int m = 0; m < 4; ++m)
#pragma unroll
      for (int n = 0; n < 4; ++n)
        acc[m][n] = __builtin_amdgcn_mfma_f32_16x16x32_bf16(af[m], bg[n], acc[m][n], 0, 0, 0);
    __syncthreads();
  }

#pragma unroll
  for (int m = 0; m < 4; ++m)
#pragma unroll
    for (int n = 0; n < 4; ++n)
#pragma unroll
      for (int r2 = 0; r2 < 4; ++r2) {
        int row = row0 + wm * 64 + m * 16 + g * 4 + r2;
        int col = col0 + wn * 64 + n * 16 + lr;
        Chi[(size_t)row * N + col] = f2bf(acc[m][n][r2] * oscale);
      }
}

// ---------------- 1-term bf16 MFMA GEMM, f16 out (for V) ----------------
__global__ __launch_bounds__(256) void gemm_1h(const unsigned short* __restrict__ Ah,
                                               const unsigned short* __restrict__ Bth,
                                               unsigned short* __restrict__ Ch,
                                               int M, int N, int K) {
  __shared__ unsigned short lA[128 * 32];
  __shared__ unsigned short lB[128 * 32];
  int t = threadIdx.x;
  int row0 = blockIdx.x * 128, col0 = blockIdx.y * 128;
  int w = t >> 6, lane = t & 63;
  int wm = w >> 1, wn = w & 1;
  int lr = lane & 15, g = lane >> 4;

  f32x4 acc[4][4] = {};

  for (int kt = 0; kt < K; kt += 32) {
#pragma unroll
    for (int cc = 0; cc < 2; ++cc) {
      int chunk = cc * 4 + w;
      int Lb = chunk * 1024;
      int L = Lb + lane * 16;
      int rr = L >> 6;
      int kc = (L & 63) >> 1;
      size_t offA = (size_t)(row0 + rr) * K + kt + kc;
      size_t offB = (size_t)(col0 + rr) * K + kt + kc;
      gl16(Ah + offA, lA + Lb / 2);
      gl16(Bth + offB, lB + Lb / 2);
    }
    __syncthreads();
    bf16x8 af[4], bg[4];
#pragma unroll
    for (int m = 0; m < 4; ++m) af[m] = *(const bf16x8*)&lA[(wm * 64 + m * 16 + lr) * 32 + g * 8];
#pragma unroll
    for (int n = 0; n < 4; ++n) bg[n] = *(const bf16x8*)&lB[(wn * 64 + n * 16 + lr) * 32 + g * 8];
#pragma unroll
    for (int m = 0; m < 4; ++m)
#pragma unroll
      for (int n = 0; n < 4; ++n)
        acc[m][n] = __builtin_amdgcn_mfma_f32_16x16x32_bf16(af[m], bg[n], acc[m][n], 0, 0, 0);
    __syncthreads();
  }

#pragma unroll
  for (int m = 0; m < 4; ++m)
#pragma unroll
    for (int n = 0; n < 4; ++n)
#pragma unroll
      for (int r2 = 0; r2 < 4; ++r2) {
        int row = row0 + wm * 64 + m * 16 + g * 4 + r2;
        int col = col0 + wn * 64 + n * 16 + lr;
        __half hv = __float2half(acc[m][n][r2]);
        Ch[(size_t)row * N + col] = __half_as_ushort(hv);
      }
}

// ---------------- 1-term bf16 MFMA GEMM: Cf = Ah * Bth^T (f32 out) ----------------
__global__ __launch_bounds__(256) void gemm_1f(const unsigned short* __restrict__ Ah,
                                               const unsigned short* __restrict__ Bth,
                                               float* __restrict__ Cf,
                                               int M, int N, int K) {
  __shared__ unsigned short lA[128 * 32];
  __shared__ unsigned short lB[128 * 32];
  int t = threadIdx.x;
  int row0 = blockIdx.x * 128, col0 = blockIdx.y * 128;
  int w = t >> 6, lane = t & 63;
  int wm = w >> 1, wn = w & 1;
  int lr = lane & 15, g = lane >> 4;

  f32x4 acc[4][4] = {};

  for (int kt = 0; kt < K; kt += 32) {
#pragma unroll
    for (int cc = 0; cc < 2; ++cc) {
      int chunk = cc * 4 + w;
      int Lb = chunk * 1024;
      int L = Lb + lane * 16;
      int rr = L >> 6;
      int kc = (L & 63) >> 1;
      size_t offA = (size_t)(row0 + rr) * K + kt + kc;
      size_t offB = (size_t)(col0 + rr) * K + kt + kc;
      gl16(Ah + offA, lA + Lb / 2);
      gl16(Bth + offB, lB + Lb / 2);
    }
    __syncthreads();
    bf16x8 af[4], bg[4];
#pragma unroll
    for (int m = 0; m < 4; ++m) af[m] = *(const bf16x8*)&lA[(wm * 64 + m * 16 + lr) * 32 + g * 8];
#pragma unroll
    for (int n = 0; n < 4; ++n) bg[n] = *(const bf16x8*)&lB[(wn * 64 + n * 16 + lr) * 32 + g * 8];
#pragma unroll
    for (int m = 0; m < 4; ++m)
#pragma unroll
      for (int n = 0; n < 4; ++n)
        acc[m][n] = __builtin_amdgcn_mfma_f32_16x16x32_bf16(af[m], bg[n], acc[m][n], 0, 0, 0);
    __syncthreads();
  }

#pragma unroll
  for (int m = 0; m < 4; ++m)
#pragma unroll
    for (int n = 0; n < 4; ++n)
#pragma unroll
      for (int r2 = 0; r2 < 4; ++r2) {
        int row = row0 + wm * 64 + m * 16 + g * 4 + r2;
        int col = col0 + wn * 64 + n * 16 + lr;
        Cf[(size_t)row * N + col] = acc[m][n][r2];
      }
}

// ---------------- fused attention: QK^T -> u16 keys -> select -> PV (f16) ----------------
// One block = (b, h, 16 query rows). 1024 threads = 16 waves; one row per wave after A.
// Marking stores (j<<16 | k16); forget+exp fused; PV: zero-padded 4-deep hfma2 gather.
__global__ __launch_bounds__(1024, 8) void attn_fused(const unsigned short* __restrict__ qh,
                                                      const unsigned short* __restrict__ kh,
                                                      const unsigned short* __restrict__ vhf,
                                                      const int* __restrict__ forget,
                                                      unsigned short* __restrict__ oh) {
  __shared__ unsigned short keys[16][KST];    // 65.7 KB: mono(score)>>16
  __shared__ unsigned int scratch[16][224];   // 14.3 KB: hist then packed lists

  int bid = blockIdx.x;
  int bh = bid >> 7;
  int tile = 127 - (bid & 127);               // big tiles dispatched first
  int b = bh >> 4, h = bh & 15;
  int i0 = tile * 16;
  int t = threadIdx.x;
  int w = t >> 6, lane = t & 63;
  int lr = lane & 15, g = lane >> 4;

  scratch[w][lane] = 0;
  scratch[w][lane + 64] = 0;
  __syncthreads();

  // ---- Phase A: QK^T (1-term bf16) + fused pass-0 histogram ----
  size_t qbase = ((size_t)(b * S_ + i0 + lr)) * HD_ + h * DH_;
  bf16x8 aq[4];
#pragma unroll
  for (int ks = 0; ks < 4; ++ks) aq[ks] = *(const bf16x8*)(qh + qbase + ks * 32 + g * 8);

  for (int kblk = w; kblk <= tile; kblk += 16) {
    int j0 = kblk * 16;
    size_t kbase = ((size_t)(b * S_ + j0 + lr)) * HD_ + h * DH_;
    f32x4 acc = {0.f, 0.f, 0.f, 0.f};
#pragma unroll
    for (int ks = 0; ks < 4; ++ks) {
      bf16x8 bk = *(const bf16x8*)(kh + kbase + ks * 32 + g * 8);
      acc = __builtin_amdgcn_mfma_f32_16x16x32_bf16(aq[ks], bk, acc, 0, 0, 0);
    }
    int j = j0 + lr;
#pragma unroll
    for (int r2 = 0; r2 < 4; ++r2) {
      int rr = g * 4 + r2;
      unsigned int k16 = mono(acc[r2]) >> 16;
      keys[rr][j] = (unsigned short)k16;
      int irow = i0 + rr;
      if (j >= SINKS_ && j <= irow - WINDOW_) {
        unsigned int bkt = k16 >> 8;
        atomicAdd(&scratch[rr][bkt >> 1], 1u << ((bkt & 1u) * 16));
      }
    }
  }
  __syncthreads();

  // ---- Phase B: wave-private row select on u16 keys ----
  int r = w;
  int i = i0 + r;
  size_t rsg = (size_t)bh * S_ + i;

  int hi = i - WINDOW_;
  int C = hi - SINKS_ + 1;
  int mode = (C <= 0) ? 0 : (C <= KTOP_ ? 1 : 2);
  unsigned int T16 = 0; int neq = 0;

  if (mode == 2) {
    int cmax = hi >> 6;
    unsigned int need = KTOP_;
    unsigned int d0_, d1_;
    // pass 0: reduce the histogram Phase A already built
    {
      unsigned int w0 = scratch[r][lane * 2], w1 = scratch[r][lane * 2 + 1];
      unsigned int s0 = (w0 & 0xffffu) + (w0 >> 16) + (w1 & 0xffffu) + (w1 >> 16);
      unsigned int suf = s0;
#pragma unroll
      for (int off = 1; off < 64; off <<= 1) {
        unsigned int vv = __shfl_down(suf, off);
        if (lane + off < 64) suf += vv;
      }
      unsigned int sufn = __shfl_down(suf, 1);
      if (lane == 63) sufn = 0;
      bool pl = (suf >= need) && (sufn < need);
      unsigned long long bal = __ballot(pl);
      int gg = __ffsll(bal) - 1;
      unsigned int basec = __shfl(sufn, gg);
      unsigned int cum = basec; int dstar = 4 * gg;
#pragma unroll
      for (int dd = 3; dd >= 0; --dd) {
        int d = 4 * gg + dd;
        unsigned int hd = (scratch[r][d >> 1] >> ((d & 1) * 16)) & 0xffffu;
        cum += hd;
        if (cum >= need) { dstar = d; break; }
      }
      unsigned int hstar = (scratch[r][dstar >> 1] >> ((dstar & 1) * 16)) & 0xffffu;
      need -= (cum - hstar);
      d0_ = (unsigned int)dstar;
    }
    // pass 1: low 8 bits among keys with high byte == d0_
    scratch[r][lane] = 0; scratch[r][lane + 64] = 0;
    for (int c = 0; c <= cmax; ++c) {
      int j = c * 64 + lane;
      unsigned int key = keys[r][j];
      bool cand = (j >= SINKS_) && (j <= hi);
      if (cand && (key >> 8) == d0_) {
        unsigned int bkt = key & 255u;
        atomicAdd(&scratch[r][bkt >> 1], 1u << ((bkt & 1u) * 16));
      }
    }
    {
      unsigned int w0 = scratch[r][lane * 2], w1 = scratch[r][lane * 2 + 1];
      unsigned int s0 = (w0 & 0xffffu) + (w0 >> 16) + (w1 & 0xffffu) + (w1 >> 16);
      unsigned int suf = s0;
#pragma unroll
      for (int off = 1; off < 64; off <<= 1) {
        unsigned int vv = __shfl_down(suf, off);
        if (lane + off < 64) suf += vv;
      }
      unsigned int sufn = __shfl_down(suf, 1);
      if (lane == 63) sufn = 0;
      bool pl = (suf >= need) && (sufn < need);
      unsigned long long bal = __ballot(pl);
      int gg = __ffsll(bal) - 1;
      unsigned int basec = __shfl(sufn, gg);
      unsigned int cum = basec; int dstar = 4 * gg;
#pragma unroll
      for (int dd = 3; dd >= 0; --dd) {
        int d = 4 * gg + dd;
        unsigned int hd = (scratch[r][d >> 1] >> ((d & 1) * 16)) & 0xffffu;
        cum += hd;
        if (cum >= need) { dstar = d; break; }
      }
      unsigned int hstar = (scratch[r][dstar >> 1] >> ((dstar & 1) * 16)) & 0xffffu;
      need -= (cum - hstar);
      d1_ = (unsigned int)dstar;
    }
    T16 = (d0_ << 8) | d1_;
    neq = (int)need;
  }

  // marking + compaction (region-split; stores j<<16|k16; ties ascending)
  int neq_run = neq;
  int cnt = 0;
  int nch = i >> 6;
  int cfull_end = (mode == 2) ? ((hi + 1) >> 6) : 0;
  for (int c = 0; c <= nch; ++c) {
    int j = c * 64 + lane;
    unsigned int k16v = keys[r][j];
    if (mode != 2 || c * 64 > hi) {
      if (c * 64 + 63 <= i) {
        // full window/sink chunk: all 64 lanes allowed -> direct write
        scratch[r][cnt + lane] = ((unsigned int)j << 16) | k16v;
        cnt += 64;
      } else {
        bool allowed = j <= i;
        unsigned long long am = __ballot(allowed);
        if (allowed) {
          int pos = cnt + __popcll(am & ((1ull << lane) - 1ull));
          scratch[r][pos] = ((unsigned int)j << 16) | k16v;
        }
        cnt += __popcll(am);
      }
    } else if (c >= 1 && c < cfull_end) {
      bool sel = k16v > T16;
      if (neq_run > 0) {
        bool iseq = (k16v == T16);
        unsigned long long em = __ballot(iseq);
        if (iseq) {
          int rk = __popcll(em & ((1ull << lane) - 1ull));
          if (rk < neq_run) sel = true;
        }
        int taken = __popcll(em);
        neq_run -= (taken < neq_run) ? taken : neq_run;
      }
      unsigned long long am = __ballot(sel);
      if (sel) {
        int pos = cnt + __popcll(am & ((1ull << lane) - 1ull));
        scratch[r][pos] = ((unsigned int)j << 16) | k16v;
      }
      cnt += __popcll(am);
    } else {
      bool valid = j <= i;
      bool isbase = valid && ((j < SINKS_) || ((i - j) < WINDOW_));
      bool iscand = valid && !isbase;
      bool sel = false, iseq = false;
      if (iscand) {
        sel = k16v > T16;
        iseq = (k16v == T16);
      }
      unsigned long long em = __ballot(iseq);
      if (iseq) {
        int rk = __popcll(em & ((1ull << lane) - 1ull));
        if (rk < neq_run) sel = true;
      }
      int taken = __popcll(em);
      neq_run -= (taken < neq_run) ? taken : neq_run;
      bool allowed = isbase || sel;
      unsigned long long am = __ballot(allowed);
      if (allowed) {
        int pos = cnt + __popcll(am & ((1ull << lane) - 1ull));
        scratch[r][pos] = ((unsigned int)j << 16) | k16v;
      }
      cnt += __popcll(am);
    }
  }

  // fused forget + weights pass: scattered mask reads ONLY for selected candidates;
  // recompact, computing exp and packing f16 weight in the same pass.
  float sum = 0.f;
  {
    const int* frow = forget + rsg * (size_t)S_;
    int newcnt = 0;
    for (int c0 = 0; c0 < cnt; c0 += 64) {
      int p = c0 + lane;
      bool active = p < cnt;
      unsigned int pk = active ? scratch[r][p] : 0u;
      int j = (int)(pk >> 16);
      bool isb = (j < SINKS_) || ((i - j) < WINDOW_);
      bool fbit = false;
      if (active && !isb) fbit = (frow[j] != 0);
      bool keep = active && !fbit;
      unsigned long long km = __ballot(keep);
      if (keep) {
        float wgt = __expf(dq16(pk & 0xffffu));
        sum += wgt;
        int npos = newcnt + __popcll(km & ((1ull << lane) - 1ull));
        scratch[r][npos] = (pk & 0xffff0000u) |
                           (unsigned int)__half_as_ushort(__float2half(wgt));
      }
      newcnt += __popcll(km);
    }
    cnt = newcnt;
  }
#pragma unroll
  for (int off = 32; off >= 1; off >>= 1) sum += __shfl_xor(sum, off);
  float inv = 1.0f / sum;

  // zero-pad to 4*qs (j=0, w=0 entries are harmless) -> PV has no remainder
  int qs = (((cnt + 3) >> 2) + 3) & ~3;       // 4-aligned quarter stride
  for (int p = cnt + lane; p < 4 * qs; p += 64) scratch[r][p] = 0;

  // ---- Phase C: PV in packed f16. 16 lanes x 8 dims; 4-aligned quarter slices ----
  int quarter = lane >> 4;
  int q16 = lane & 15;
  int d0 = q16 * 8;
  int p0 = quarter * qs;
  int p1 = p0 + qs;
  size_t vb0 = ((size_t)(b * S_)) * HD_ + h * DH_ + d0;

  __half2 A0 = __floats2half2_rn(0.f, 0.f);
  __half2 A1 = A0, A2 = A0, A3 = A0;
  __builtin_amdgcn_s_setprio(1);
  for (int p = p0; p < p1; p += 4) {
    uint4 pks = *(const uint4*)&scratch[r][p];   // 16B-aligned ds_read_b128
    int j0q = (int)(pks.x >> 16), j1q = (int)(pks.y >> 16);
    int j2q = (int)(pks.z >> 16), j3q = (int)(pks.w >> 16);
    uint4 v0 = *(const uint4*)(vhf + vb0 + (size_t)j0q * HD_);
    uint4 v1 = *(const uint4*)(vhf + vb0 + (size_t)j1q * HD_);
    uint4 v2 = *(const uint4*)(vhf + vb0 + (size_t)j2q * HD_);
    uint4 v3 = *(const uint4*)(vhf + vb0 + (size_t)j3q * HD_);
    __half2 w0 = __half2half2(__ushort_as_half((unsigned short)(pks.x & 0xffffu)));
    __half2 w1 = __half2half2(__ushort_as_half((unsigned short)(pks.y & 0xffffu)));
    __half2 w2 = __half2half2(__ushort_as_half((unsigned short)(pks.z & 0xffffu)));
    __half2 w3 = __half2half2(__ushort_as_half((unsigned short)(pks.w & 0xffffu)));
    A0 = __hfma2(w0, *(const __half2*)&v0.x, A0);
    A1 = __hfma2(w0, *(const __half2*)&v0.y, A1);
    A2 = __hfma2(w0, *(const __half2*)&v0.z, A2);
    A3 = __hfma2(w0, *(const __half2*)&v0.w, A3);
    A0 = __hfma2(w1, *(const __half2*)&v1.x, A0);
    A1 = __hfma2(w1, *(const __half2*)&v1.y, A1);
    A2 = __hfma2(w1, *(const __half2*)&v1.z, A2);
    A3 = __hfma2(w1, *(const __half2*)&v1.w, A3);
    A0 = __hfma2(w2, *(const __half2*)&v2.x, A0);
    A1 = __hfma2(w2, *(const __half2*)&v2.y, A1);
    A2 = __hfma2(w2, *(const __half2*)&v2.z, A2);
    A3 = __hfma2(w2, *(const __half2*)&v2.w, A3);
    A0 = __hfma2(w3, *(const __half2*)&v3.x, A0);
    A1 = __hfma2(w3, *(const __half2*)&v3.y, A1);
    A2 = __hfma2(w3, *(const __half2*)&v3.z, A2);
    A3 = __hfma2(w3, *(const __half2*)&v3.w, A3);
  }
  __builtin_amdgcn_s_setprio(0);
#pragma unroll
  for (int off = 16; off <= 32; off <<= 1) {
    int v0 = __shfl_xor(*(int*)&A0, off);
    int v1 = __shfl_xor(*(int*)&A1, off);
    int v2 = __shfl_xor(*(int*)&A2, off);
    int v3 = __shfl_xor(*(int*)&A3, off);
    A0 = __hadd2(A0, *(__half2*)&v0);
    A1 = __hadd2(A1, *(__half2*)&v1);
    A2 = __hadd2(A2, *(__half2*)&v2);
    A3 = __hadd2(A3, *(__half2*)&v3);
  }
  if (quarter == 0) {
    float2 f0 = __half22float2(A0), f1 = __half22float2(A1);
    float2 f2 = __half22float2(A2), f3 = __half22float2(A3);
    ushort4 h0, h1;
    h0.x = f2bf(f0.x * inv); h0.y = f2bf(f0.y * inv);
    h0.z = f2bf(f1.x * inv); h0.w = f2bf(f1.y * inv);
    h1.x = f2bf(f2.x * inv); h1.y = f2bf(f2.y * inv);
    h1.z = f2bf(f3.x * inv); h1.w = f2bf(f3.y * inv);
    size_t oidx = ((size_t)(b * S_ + i)) * HD_ + h * DH_ + d0;
    *(ushort4*)(oh + oidx) = h0;
    *(ushort4*)(oh + oidx + 4) = h1;
  }
}

extern "C" void kernel_launch(void* const* d_in, const int* in_sizes, int n_in,
                              void* d_out, int out_size, void* d_ws, size_t ws_size,
                              hipStream_t stream) {
  (void)in_sizes; (void)n_in; (void)out_size; (void)ws_size;
  const float* x  = (const float*)d_in[0];
  const float* Wq = (const float*)d_in[1];
  const float* Wc = (const float*)d_in[2];
  const float* Wk = (const float*)d_in[3];
  const float* Wv = (const float*)d_in[4];
  const float* Wo = (const float*)d_in[5];
  const int* forget = (const int*)d_in[6];  // bool widened to int32 (verified r3)

  char* ws = (char*)d_ws;
  size_t off = 0;
  auto alloc = [&](size_t bytes) { char* p = ws + off; off += (bytes + 255) & ~(size_t)255; return p; };

  unsigned short* x_bf = (unsigned short*)alloc((size_t)4096 * 2048 * 2);  // reused as o
  unsigned short* WqT  = (unsigned short*)alloc((size_t)2048 * 2048 * 2);
  unsigned short* WcTh = (unsigned short*)alloc((size_t)512 * 2048 * 2);
  unsigned short* WcTl = (unsigned short*)alloc((size_t)512 * 2048 * 2);
  unsigned short* WkT  = (unsigned short*)alloc((size_t)2048 * 512 * 2);
  unsigned short* WvT  = (unsigned short*)alloc((size_t)2048 * 512 * 2);
  unsigned short* WoT  = (unsigned short*)alloc((size_t)2048 * 2048 * 2);
  unsigned short* q_hi = (unsigned short*)alloc((size_t)4096 * 2048 * 2);
  unsigned short* c_hi = (unsigned short*)alloc((size_t)4096 * 512 * 2);
  unsigned short* k_hi = (unsigned short*)alloc((size_t)4096 * 2048 * 2);
  unsigned short* v_hf = (unsigned short*)alloc((size_t)4096 * 2048 * 2);

  unsigned short* o_hi = x_bf;

  const float scale = 0.08838834764831845f;

  prep_all<<<13312, 256, 0, stream>>>(x, Wq, Wc, Wk, Wv, Wo,
                                      x_bf, WqT, WcTh, WcTl, WkT, WvT, WoT);

  gemm_c64<<<dim3(64, 4), 256, 0, stream>>>(x_bf, WcTh, WcTl, c_hi, 4096, 512, 2048);
  gemm_1term<<<dim3(32, 16), 256, 0, stream>>>(x_bf, WqT, q_hi, 4096, 2048, 2048, scale);
  gemm_1term<<<dim3(32, 16), 256, 0, stream>>>(c_hi, WkT, k_hi, 4096, 2048, 512, 1.0f);
  gemm_1h<<<dim3(32, 16), 256, 0, stream>>>(c_hi, WvT, v_hf, 4096, 2048, 512);

  attn_fused<<<4096, 1024, 0, stream>>>(q_hi, k_hi, v_hf, forget, o_hi);

  gemm_1f<<<dim3(32, 16), 256, 0, stream>>>(o_hi, WoT, (float*)d_out, 4096, 2048, 2048);
}

// Round 22
// 532.300 us; speedup vs baseline: 1.0980x; 1.0762x over previous
//
#include <hip/hip_runtime.h>
#include <hip/hip_fp16.h>

#define B_ 2
#define S_ 2048
#define HD_ 2048
#define NH_ 16
#define DH_ 128
#define L_ 512
#define WINDOW_ 128
#define SINKS_ 16
#define KTOP_ 64
#define KST 2052   /* keys[] row stride in u16 */

typedef __attribute__((ext_vector_type(4))) float f32x4;
typedef __attribute__((ext_vector_type(8))) __bf16 bf16x8;

__device__ inline unsigned short f2bf(float f) {
  unsigned int u = __float_as_uint(f);
  unsigned int r = (u + 0x7FFFu + ((u >> 16) & 1u)) >> 16;
  return (unsigned short)r;
}
__device__ inline float bf2f(unsigned short u) {
  unsigned int x = ((unsigned int)u) << 16;
  return __uint_as_float(x);
}
__device__ inline unsigned int mono(float f) {
  unsigned int u = __float_as_uint(f);
  return (u & 0x80000000u) ? ~u : (u | 0x80000000u);
}
// midpoint dequant of a 16-bit mono key back to float
__device__ inline float dq16(unsigned int k16) {
  unsigned int m = (k16 << 16) | 0x8000u;
  unsigned int u = (m & 0x80000000u) ? (m & 0x7fffffffu) : ~m;
  return __uint_as_float(u);
}
__device__ inline void gl16(const unsigned short* g, unsigned short* l) {
  __builtin_amdgcn_global_load_lds(
      (const __attribute__((address_space(1))) unsigned int*)g,
      (__attribute__((address_space(3))) unsigned int*)l, 16, 0, 0);
}

// ---------------- merged preprocessing: cast x + 5 weight transposes ----------------
__device__ inline void trans_cast_dev(const float* __restrict__ W,
                                      unsigned short* __restrict__ WT,
                                      int K, int N, int bx, int by, int t,
                                      unsigned short th[32][33]) {
  int n0 = bx * 32, k0 = by * 32;
  int cx = t & 31, ry = t >> 5;
#pragma unroll
  for (int it = 0; it < 4; ++it) {
    int kk = ry + it * 8;
    th[cx][kk] = f2bf(W[(size_t)(k0 + kk) * N + n0 + cx]);
  }
  __syncthreads();
#pragma unroll
  for (int it = 0; it < 4; ++it) {
    int nn = ry + it * 8;
    WT[(size_t)(n0 + nn) * K + k0 + cx] = th[nn][cx];
  }
}

__device__ inline void trans_split_dev(const float* __restrict__ W,
                                       unsigned short* __restrict__ WTh,
                                       unsigned short* __restrict__ WTl,
                                       int K, int N, int bx, int by, int t,
                                       unsigned short th[32][33],
                                       unsigned short tl[32][33]) {
  int n0 = bx * 32, k0 = by * 32;
  int cx = t & 31, ry = t >> 5;
#pragma unroll
  for (int it = 0; it < 4; ++it) {
    int kk = ry + it * 8;
    float v = W[(size_t)(k0 + kk) * N + n0 + cx];
    unsigned short h = f2bf(v);
    th[cx][kk] = h;
    tl[cx][kk] = f2bf(v - bf2f(h));
  }
  __syncthreads();
#pragma unroll
  for (int it = 0; it < 4; ++it) {
    int nn = ry + it * 8;
    WTh[(size_t)(n0 + nn) * K + k0 + cx] = th[nn][cx];
    WTl[(size_t)(n0 + nn) * K + k0 + cx] = tl[nn][cx];
  }
}

__global__ __launch_bounds__(256) void prep_all(const float* __restrict__ x,
                                                const float* __restrict__ Wq,
                                                const float* __restrict__ Wc,
                                                const float* __restrict__ Wk,
                                                const float* __restrict__ Wv,
                                                const float* __restrict__ Wo,
                                                unsigned short* __restrict__ x_bf,
                                                unsigned short* __restrict__ WqT,
                                                unsigned short* __restrict__ WcTh,
                                                unsigned short* __restrict__ WcTl,
                                                unsigned short* __restrict__ WkT,
                                                unsigned short* __restrict__ WvT,
                                                unsigned short* __restrict__ WoT) {
  __shared__ unsigned short th[32][33];
  __shared__ unsigned short tl[32][33];
  int bid = blockIdx.x;
  int t = threadIdx.x;
  if (bid < 2048) {
    const int n = 4096 * 2048;
    const int stride = 2048 * 256 * 4;
    for (int i = (bid * 256 + t) * 4; i < n; i += stride) {
      float4 v = *(const float4*)(x + i);
      ushort4 h;
      h.x = f2bf(v.x); h.y = f2bf(v.y); h.z = f2bf(v.z); h.w = f2bf(v.w);
      *(ushort4*)(x_bf + i) = h;
    }
  } else if (bid < 2048 + 4096) {
    int bb = bid - 2048;
    trans_cast_dev(Wq, WqT, 2048, 2048, bb & 63, bb >> 6, t, th);
  } else if (bid < 2048 + 4096 + 1024) {
    int bb = bid - (2048 + 4096);
    trans_split_dev(Wc, WcTh, WcTl, 2048, 512, bb & 15, bb >> 4, t, th, tl);
  } else if (bid < 2048 + 4096 + 2048) {
    int bb = bid - (2048 + 4096 + 1024);
    trans_cast_dev(Wk, WkT, 512, 2048, bb & 63, bb >> 6, t, th);
  } else if (bid < 2048 + 4096 + 3072) {
    int bb = bid - (2048 + 4096 + 2048);
    trans_cast_dev(Wv, WvT, 512, 2048, bb & 63, bb >> 6, t, th);
  } else {
    int bb = bid - (2048 + 4096 + 3072);
    trans_cast_dev(Wo, WoT, 2048, 2048, bb & 63, bb >> 6, t, th);
  }
}

// ---------------- 2-term GEMM, 64x128 tile: C = A * (Bth+Btl)^T, bf16 out ----------------
__global__ __launch_bounds__(256) void gemm_c64(const unsigned short* __restrict__ Ah,
                                                const unsigned short* __restrict__ Bth,
                                                const unsigned short* __restrict__ Btl,
                                                unsigned short* __restrict__ Chi,
                                                int M, int N, int K) {
  __shared__ unsigned short lAh[64 * 32];
  __shared__ unsigned short lBh[128 * 32];
  __shared__ unsigned short lBl[128 * 32];
  int t = threadIdx.x;
  int row0 = blockIdx.x * 64, col0 = blockIdx.y * 128;
  int w = t >> 6, lane = t & 63;
  int wm = w >> 1, wn = w & 1;
  int lr = lane & 15, g = lane >> 4;

  f32x4 acc[2][4] = {};

  for (int kt = 0; kt < K; kt += 32) {
    {
      int Lb = w * 1024;
      int L = Lb + lane * 16;
      int rr = L >> 6, kc = (L & 63) >> 1;
      size_t offA = (size_t)(row0 + rr) * K + kt + kc;
      gl16(Ah + offA, lAh + Lb / 2);
      int Lb0 = (2 * w) * 1024;
      int L0 = Lb0 + lane * 16;
      int rr0 = L0 >> 6, kc0 = (L0 & 63) >> 1;
      size_t offB0 = (size_t)(col0 + rr0) * K + kt + kc0;
      gl16(Bth + offB0, lBh + Lb0 / 2);
      gl16(Btl + offB0, lBl + Lb0 / 2);
      int Lb1 = (2 * w + 1) * 1024;
      int L1 = Lb1 + lane * 16;
      int rr1 = L1 >> 6, kc1 = (L1 & 63) >> 1;
      size_t offB1 = (size_t)(col0 + rr1) * K + kt + kc1;
      gl16(Bth + offB1, lBh + Lb1 / 2);
      gl16(Btl + offB1, lBl + Lb1 / 2);
    }
    __syncthreads();
    bf16x8 af[2], bgh[4], bgl[4];
#pragma unroll
    for (int m = 0; m < 2; ++m)
      af[m] = *(const bf16x8*)&lAh[(wm * 32 + m * 16 + lr) * 32 + g * 8];
#pragma unroll
    for (int n = 0; n < 4; ++n) {
      bgh[n] = *(const bf16x8*)&lBh[(wn * 64 + n * 16 + lr) * 32 + g * 8];
      bgl[n] = *(const bf16x8*)&lBl[(wn * 64 + n * 16 + lr) * 32 + g * 8];
    }
#pragma unroll
    for (int m = 0; m < 2; ++m)
#pragma unroll
      for (int n = 0; n < 4; ++n) {
        acc[m][n] = __builtin_amdgcn_mfma_f32_16x16x32_bf16(af[m], bgh[n], acc[m][n], 0, 0, 0);
        acc[m][n] = __builtin_amdgcn_mfma_f32_16x16x32_bf16(af[m], bgl[n], acc[m][n], 0, 0, 0);
      }
    __syncthreads();
  }

#pragma unroll
  for (int m = 0; m < 2; ++m)
#pragma unroll
    for (int n = 0; n < 4; ++n)
#pragma unroll
      for (int r2 = 0; r2 < 4; ++r2) {
        int row = row0 + wm * 32 + m * 16 + g * 4 + r2;
        int col = col0 + wn * 64 + n * 16 + lr;
        Chi[(size_t)row * N + col] = f2bf(acc[m][n][r2]);
      }
}

// ---------------- 1-term bf16 MFMA GEMM: C = Ah * Bth^T (bf16 out, scale) ----------------
__global__ __launch_bounds__(256) void gemm_1term(const unsigned short* __restrict__ Ah,
                                                  const unsigned short* __restrict__ Bth,
                                                  unsigned short* __restrict__ Chi,
                                                  int M, int N, int K, float oscale) {
  __shared__ unsigned short lA[128 * 32];
  __shared__ unsigned short lB[128 * 32];
  int t = threadIdx.x;
  int row0 = blockIdx.x * 128, col0 = blockIdx.y * 128;
  int w = t >> 6, lane = t & 63;
  int wm = w >> 1, wn = w & 1;
  int lr = lane & 15, g = lane >> 4;

  f32x4 acc[4][4] = {};

  for (int kt = 0; kt < K; kt += 32) {
#pragma unroll
    for (int cc = 0; cc < 2; ++cc) {
      int chunk = cc * 4 + w;
      int Lb = chunk * 1024;
      int L = Lb + lane * 16;
      int rr = L >> 6;
      int kc = (L & 63) >> 1;
      size_t offA = (size_t)(row0 + rr) * K + kt + kc;
      size_t offB = (size_t)(col0 + rr) * K + kt + kc;
      gl16(Ah + offA, lA + Lb / 2);
      gl16(Bth + offB, lB + Lb / 2);
    }
    __syncthreads();
    bf16x8 af[4], bg[4];
#pragma unroll
    for (int m = 0; m < 4; ++m) af[m] = *(const bf16x8*)&lA[(wm * 64 + m * 16 + lr) * 32 + g * 8];
#pragma unroll
    for (int n = 0; n < 4; ++n) bg[n] = *(const bf16x8*)&lB[(wn * 64 + n * 16 + lr) * 32 + g * 8];
#pragma unroll
    for (int m = 0; m < 4; ++m)
#pragma unroll
      for (int n = 0; n < 4; ++n)
        acc[m][n] = __builtin_amdgcn_mfma_f32_16x16x32_bf16(af[m], bg[n], acc[m][n], 0, 0, 0);
    __syncthreads();
  }

#pragma unroll
  for (int m = 0; m < 4; ++m)
#pragma unroll
    for (int n = 0; n < 4; ++n)
#pragma unroll
      for (int r2 = 0; r2 < 4; ++r2) {
        int row = row0 + wm * 64 + m * 16 + g * 4 + r2;
        int col = col0 + wn * 64 + n * 16 + lr;
        Chi[(size_t)row * N + col] = f2bf(acc[m][n][r2] * oscale);
      }
}

// ---------------- 1-term bf16 MFMA GEMM, f16 out (for V) ----------------
__global__ __launch_bounds__(256) void gemm_1h(const unsigned short* __restrict__ Ah,
                                               const unsigned short* __restrict__ Bth,
                                               unsigned short* __restrict__ Ch,
                                               int M, int N, int K) {
  __shared__ unsigned short lA[128 * 32];
  __shared__ unsigned short lB[128 * 32];
  int t = threadIdx.x;
  int row0 = blockIdx.x * 128, col0 = blockIdx.y * 128;
  int w = t >> 6, lane = t & 63;
  int wm = w >> 1, wn = w & 1;
  int lr = lane & 15, g = lane >> 4;

  f32x4 acc[4][4] = {};

  for (int kt = 0; kt < K; kt += 32) {
#pragma unroll
    for (int cc = 0; cc < 2; ++cc) {
      int chunk = cc * 4 + w;
      int Lb = chunk * 1024;
      int L = Lb + lane * 16;
      int rr = L >> 6;
      int kc = (L & 63) >> 1;
      size_t offA = (size_t)(row0 + rr) * K + kt + kc;
      size_t offB = (size_t)(col0 + rr) * K + kt + kc;
      gl16(Ah + offA, lA + Lb / 2);
      gl16(Bth + offB, lB + Lb / 2);
    }
    __syncthreads();
    bf16x8 af[4], bg[4];
#pragma unroll
    for (int m = 0; m < 4; ++m) af[m] = *(const bf16x8*)&lA[(wm * 64 + m * 16 + lr) * 32 + g * 8];
#pragma unroll
    for (int n = 0; n < 4; ++n) bg[n] = *(const bf16x8*)&lB[(wn * 64 + n * 16 + lr) * 32 + g * 8];
#pragma unroll
    for (int m = 0; m < 4; ++m)
#pragma unroll
      for (int n = 0; n < 4; ++n)
        acc[m][n] = __builtin_amdgcn_mfma_f32_16x16x32_bf16(af[m], bg[n], acc[m][n], 0, 0, 0);
    __syncthreads();
  }

#pragma unroll
  for (int m = 0; m < 4; ++m)
#pragma unroll
    for (int n = 0; n < 4; ++n)
#pragma unroll
      for (int r2 = 0; r2 < 4; ++r2) {
        int row = row0 + wm * 64 + m * 16 + g * 4 + r2;
        int col = col0 + wn * 64 + n * 16 + lr;
        __half hv = __float2half(acc[m][n][r2]);
        Ch[(size_t)row * N + col] = __half_as_ushort(hv);
      }
}

// ---------------- 1-term bf16 MFMA GEMM: Cf = Ah * Bth^T (f32 out) ----------------
__global__ __launch_bounds__(256) void gemm_1f(const unsigned short* __restrict__ Ah,
                                               const unsigned short* __restrict__ Bth,
                                               float* __restrict__ Cf,
                                               int M, int N, int K) {
  __shared__ unsigned short lA[128 * 32];
  __shared__ unsigned short lB[128 * 32];
  int t = threadIdx.x;
  int row0 = blockIdx.x * 128, col0 = blockIdx.y * 128;
  int w = t >> 6, lane = t & 63;
  int wm = w >> 1, wn = w & 1;
  int lr = lane & 15, g = lane >> 4;

  f32x4 acc[4][4] = {};

  for (int kt = 0; kt < K; kt += 32) {
#pragma unroll
    for (int cc = 0; cc < 2; ++cc) {
      int chunk = cc * 4 + w;
      int Lb = chunk * 1024;
      int L = Lb + lane * 16;
      int rr = L >> 6;
      int kc = (L & 63) >> 1;
      size_t offA = (size_t)(row0 + rr) * K + kt + kc;
      size_t offB = (size_t)(col0 + rr) * K + kt + kc;
      gl16(Ah + offA, lA + Lb / 2);
      gl16(Bth + offB, lB + Lb / 2);
    }
    __syncthreads();
    bf16x8 af[4], bg[4];
#pragma unroll
    for (int m = 0; m < 4; ++m) af[m] = *(const bf16x8*)&lA[(wm * 64 + m * 16 + lr) * 32 + g * 8];
#pragma unroll
    for (int n = 0; n < 4; ++n) bg[n] = *(const bf16x8*)&lB[(wn * 64 + n * 16 + lr) * 32 + g * 8];
#pragma unroll
    for (int m = 0; m < 4; ++m)
#pragma unroll
      for (int n = 0; n < 4; ++n)
        acc[m][n] = __builtin_amdgcn_mfma_f32_16x16x32_bf16(af[m], bg[n], acc[m][n], 0, 0, 0);
    __syncthreads();
  }

#pragma unroll
  for (int m = 0; m < 4; ++m)
#pragma unroll
    for (int n = 0; n < 4; ++n)
#pragma unroll
      for (int r2 = 0; r2 < 4; ++r2) {
        int row = row0 + wm * 64 + m * 16 + g * 4 + r2;
        int col = col0 + wn * 64 + n * 16 + lr;
        Cf[(size_t)row * N + col] = acc[m][n][r2];
      }
}

// ---------------- fused attention: QK^T -> u16 keys -> select -> PV (f16) ----------------
// One block = (b, h, 16 query rows). 1024 threads = 16 waves; one row per wave after A.
// XCD-aware bijective swizzle: each XCD owns 4 contiguous heads (K/V panels L2-resident).
__global__ __launch_bounds__(1024, 8) void attn_fused(const unsigned short* __restrict__ qh,
                                                      const unsigned short* __restrict__ kh,
                                                      const unsigned short* __restrict__ vhf,
                                                      const int* __restrict__ forget,
                                                      unsigned short* __restrict__ oh) {
  __shared__ unsigned short keys[16][KST];    // 65.7 KB: mono(score)>>16
  __shared__ unsigned int scratch[16][224];   // 14.3 KB: hist then packed lists

  int orig = blockIdx.x;
  int bid = (orig & 7) * 512 + (orig >> 3);   // XCD swizzle (4096 % 8 == 0 -> bijective)
  int bh = bid >> 7;
  int tile = 127 - (bid & 127);               // big tiles dispatched first per XCD
  int b = bh >> 4, h = bh & 15;
  int i0 = tile * 16;
  int t = threadIdx.x;
  int w = t >> 6, lane = t & 63;
  int lr = lane & 15, g = lane >> 4;

  scratch[w][lane] = 0;
  scratch[w][lane + 64] = 0;
  __syncthreads();

  // ---- Phase A: QK^T (1-term bf16) + fused pass-0 histogram ----
  size_t qbase = ((size_t)(b * S_ + i0 + lr)) * HD_ + h * DH_;
  bf16x8 aq[4];
#pragma unroll
  for (int ks = 0; ks < 4; ++ks) aq[ks] = *(const bf16x8*)(qh + qbase + ks * 32 + g * 8);

  for (int kblk = w; kblk <= tile; kblk += 16) {
    int j0 = kblk * 16;
    size_t kbase = ((size_t)(b * S_ + j0 + lr)) * HD_ + h * DH_;
    f32x4 acc = {0.f, 0.f, 0.f, 0.f};
#pragma unroll
    for (int ks = 0; ks < 4; ++ks) {
      bf16x8 bk = *(const bf16x8*)(kh + kbase + ks * 32 + g * 8);
      acc = __builtin_amdgcn_mfma_f32_16x16x32_bf16(aq[ks], bk, acc, 0, 0, 0);
    }
    int j = j0 + lr;
#pragma unroll
    for (int r2 = 0; r2 < 4; ++r2) {
      int rr = g * 4 + r2;
      unsigned int k16 = mono(acc[r2]) >> 16;
      keys[rr][j] = (unsigned short)k16;
      int irow = i0 + rr;
      if (j >= SINKS_ && j <= irow - WINDOW_) {
        unsigned int bkt = k16 >> 8;
        atomicAdd(&scratch[rr][bkt >> 1], 1u << ((bkt & 1u) * 16));
      }
    }
  }
  __syncthreads();

  // ---- Phase B: wave-private row select on u16 keys ----
  int r = w;
  int i = i0 + r;
  size_t rsg = (size_t)bh * S_ + i;

  int hi = i - WINDOW_;
  int C = hi - SINKS_ + 1;
  int mode = (C <= 0) ? 0 : (C <= KTOP_ ? 1 : 2);
  unsigned int T16 = 0; int neq = 0;

  if (mode == 2) {
    int cmax = hi >> 6;
    unsigned int need = KTOP_;
    unsigned int d0_, d1_;
    // pass 0: reduce the histogram Phase A already built
    {
      unsigned int w0 = scratch[r][lane * 2], w1 = scratch[r][lane * 2 + 1];
      unsigned int s0 = (w0 & 0xffffu) + (w0 >> 16) + (w1 & 0xffffu) + (w1 >> 16);
      unsigned int suf = s0;
#pragma unroll
      for (int off = 1; off < 64; off <<= 1) {
        unsigned int vv = __shfl_down(suf, off);
        if (lane + off < 64) suf += vv;
      }
      unsigned int sufn = __shfl_down(suf, 1);
      if (lane == 63) sufn = 0;
      bool pl = (suf >= need) && (sufn < need);
      unsigned long long bal = __ballot(pl);
      int gg = __ffsll(bal) - 1;
      unsigned int basec = __shfl(sufn, gg);
      unsigned int cum = basec; int dstar = 4 * gg;
#pragma unroll
      for (int dd = 3; dd >= 0; --dd) {
        int d = 4 * gg + dd;
        unsigned int hd = (scratch[r][d >> 1] >> ((d & 1) * 16)) & 0xffffu;
        cum += hd;
        if (cum >= need) { dstar = d; break; }
      }
      unsigned int hstar = (scratch[r][dstar >> 1] >> ((dstar & 1) * 16)) & 0xffffu;
      need -= (cum - hstar);
      d0_ = (unsigned int)dstar;
    }
    // pass 1: low 8 bits among keys with high byte == d0_
    scratch[r][lane] = 0; scratch[r][lane + 64] = 0;
    for (int c = 0; c <= cmax; ++c) {
      int j = c * 64 + lane;
      unsigned int key = keys[r][j];
      bool cand = (j >= SINKS_) && (j <= hi);
      if (cand && (key >> 8) == d0_) {
        unsigned int bkt = key & 255u;
        atomicAdd(&scratch[r][bkt >> 1], 1u << ((bkt & 1u) * 16));
      }
    }
    {
      unsigned int w0 = scratch[r][lane * 2], w1 = scratch[r][lane * 2 + 1];
      unsigned int s0 = (w0 & 0xffffu) + (w0 >> 16) + (w1 & 0xffffu) + (w1 >> 16);
      unsigned int suf = s0;
#pragma unroll
      for (int off = 1; off < 64; off <<= 1) {
        unsigned int vv = __shfl_down(suf, off);
        if (lane + off < 64) suf += vv;
      }
      unsigned int sufn = __shfl_down(suf, 1);
      if (lane == 63) sufn = 0;
      bool pl = (suf >= need) && (sufn < need);
      unsigned long long bal = __ballot(pl);
      int gg = __ffsll(bal) - 1;
      unsigned int basec = __shfl(sufn, gg);
      unsigned int cum = basec; int dstar = 4 * gg;
#pragma unroll
      for (int dd = 3; dd >= 0; --dd) {
        int d = 4 * gg + dd;
        unsigned int hd = (scratch[r][d >> 1] >> ((d & 1) * 16)) & 0xffffu;
        cum += hd;
        if (cum >= need) { dstar = d; break; }
      }
      unsigned int hstar = (scratch[r][dstar >> 1] >> ((dstar & 1) * 16)) & 0xffffu;
      need -= (cum - hstar);
      d1_ = (unsigned int)dstar;
    }
    T16 = (d0_ << 8) | d1_;
    neq = (int)need;
  }

  // marking + compaction (region-split; stores j<<16|k16; ties ascending)
  int neq_run = neq;
  int cnt = 0;
  int nch = i >> 6;
  int cfull_end = (mode == 2) ? ((hi + 1) >> 6) : 0;
  for (int c = 0; c <= nch; ++c) {
    int j = c * 64 + lane;
    unsigned int k16v = keys[r][j];
    if (mode != 2 || c * 64 > hi) {
      if (c * 64 + 63 <= i) {
        scratch[r][cnt + lane] = ((unsigned int)j << 16) | k16v;
        cnt += 64;
      } else {
        bool allowed = j <= i;
        unsigned long long am = __ballot(allowed);
        if (allowed) {
          int pos = cnt + __popcll(am & ((1ull << lane) - 1ull));
          scratch[r][pos] = ((unsigned int)j << 16) | k16v;
        }
        cnt += __popcll(am);
      }
    } else if (c >= 1 && c < cfull_end) {
      bool sel = k16v > T16;
      if (neq_run > 0) {
        bool iseq = (k16v == T16);
        unsigned long long em = __ballot(iseq);
        if (iseq) {
          int rk = __popcll(em & ((1ull << lane) - 1ull));
          if (rk < neq_run) sel = true;
        }
        int taken = __popcll(em);
        neq_run -= (taken < neq_run) ? taken : neq_run;
      }
      unsigned long long am = __ballot(sel);
      if (sel) {
        int pos = cnt + __popcll(am & ((1ull << lane) - 1ull));
        scratch[r][pos] = ((unsigned int)j << 16) | k16v;
      }
      cnt += __popcll(am);
    } else {
      bool valid = j <= i;
      bool isbase = valid && ((j < SINKS_) || ((i - j) < WINDOW_));
      bool iscand = valid && !isbase;
      bool sel = false, iseq = false;
      if (iscand) {
        sel = k16v > T16;
        iseq = (k16v == T16);
      }
      unsigned long long em = __ballot(iseq);
      if (iseq) {
        int rk = __popcll(em & ((1ull << lane) - 1ull));
        if (rk < neq_run) sel = true;
      }
      int taken = __popcll(em);
      neq_run -= (taken < neq_run) ? taken : neq_run;
      bool allowed = isbase || sel;
      unsigned long long am = __ballot(allowed);
      if (allowed) {
        int pos = cnt + __popcll(am & ((1ull << lane) - 1ull));
        scratch[r][pos] = ((unsigned int)j << 16) | k16v;
      }
      cnt += __popcll(am);
    }
  }

  // fused forget + weights pass
  float sum = 0.f;
  {
    const int* frow = forget + rsg * (size_t)S_;
    int newcnt = 0;
    for (int c0 = 0; c0 < cnt; c0 += 64) {
      int p = c0 + lane;
      bool active = p < cnt;
      unsigned int pk = active ? scratch[r][p] : 0u;
      int j = (int)(pk >> 16);
      bool isb = (j < SINKS_) || ((i - j) < WINDOW_);
      bool fbit = false;
      if (active && !isb) fbit = (frow[j] != 0);
      bool keep = active && !fbit;
      unsigned long long km = __ballot(keep);
      if (keep) {
        float wgt = __expf(dq16(pk & 0xffffu));
        sum += wgt;
        int npos = newcnt + __popcll(km & ((1ull << lane) - 1ull));
        scratch[r][npos] = (pk & 0xffff0000u) |
                           (unsigned int)__half_as_ushort(__float2half(wgt));
      }
      newcnt += __popcll(km);
    }
    cnt = newcnt;
  }
#pragma unroll
  for (int off = 32; off >= 1; off >>= 1) sum += __shfl_xor(sum, off);
  float inv = 1.0f / sum;

  // zero-pad to 4*qs -> PV has no remainder
  int qs = (((cnt + 3) >> 2) + 3) & ~3;
  for (int p = cnt + lane; p < 4 * qs; p += 64) scratch[r][p] = 0;

  // ---- Phase C: PV in packed f16. 16 lanes x 8 dims; 4-aligned quarter slices ----
  int quarter = lane >> 4;
  int q16 = lane & 15;
  int d0 = q16 * 8;
  int p0 = quarter * qs;
  int p1 = p0 + qs;
  size_t vb0 = ((size_t)(b * S_)) * HD_ + h * DH_ + d0;

  __half2 A0 = __floats2half2_rn(0.f, 0.f);
  __half2 A1 = A0, A2 = A0, A3 = A0;
  __builtin_amdgcn_s_setprio(1);
  for (int p = p0; p < p1; p += 4) {
    uint4 pks = *(const uint4*)&scratch[r][p];
    int j0q = (int)(pks.x >> 16), j1q = (int)(pks.y >> 16);
    int j2q = (int)(pks.z >> 16), j3q = (int)(pks.w >> 16);
    uint4 v0 = *(const uint4*)(vhf + vb0 + (size_t)j0q * HD_);
    uint4 v1 = *(const uint4*)(vhf + vb0 + (size_t)j1q * HD_);
    uint4 v2 = *(const uint4*)(vhf + vb0 + (size_t)j2q * HD_);
    uint4 v3 = *(const uint4*)(vhf + vb0 + (size_t)j3q * HD_);
    __half2 w0 = __half2half2(__ushort_as_half((unsigned short)(pks.x & 0xffffu)));
    __half2 w1 = __half2half2(__ushort_as_half((unsigned short)(pks.y & 0xffffu)));
    __half2 w2 = __half2half2(__ushort_as_half((unsigned short)(pks.z & 0xffffu)));
    __half2 w3 = __half2half2(__ushort_as_half((unsigned short)(pks.w & 0xffffu)));
    A0 = __hfma2(w0, *(const __half2*)&v0.x, A0);
    A1 = __hfma2(w0, *(const __half2*)&v0.y, A1);
    A2 = __hfma2(w0, *(const __half2*)&v0.z, A2);
    A3 = __hfma2(w0, *(const __half2*)&v0.w, A3);
    A0 = __hfma2(w1, *(const __half2*)&v1.x, A0);
    A1 = __hfma2(w1, *(const __half2*)&v1.y, A1);
    A2 = __hfma2(w1, *(const __half2*)&v1.z, A2);
    A3 = __hfma2(w1, *(const __half2*)&v1.w, A3);
    A0 = __hfma2(w2, *(const __half2*)&v2.x, A0);
    A1 = __hfma2(w2, *(const __half2*)&v2.y, A1);
    A2 = __hfma2(w2, *(const __half2*)&v2.z, A2);
    A3 = __hfma2(w2, *(const __half2*)&v2.w, A3);
    A0 = __hfma2(w3, *(const __half2*)&v3.x, A0);
    A1 = __hfma2(w3, *(const __half2*)&v3.y, A1);
    A2 = __hfma2(w3, *(const __half2*)&v3.z, A2);
    A3 = __hfma2(w3, *(const __half2*)&v3.w, A3);
  }
  __builtin_amdgcn_s_setprio(0);
#pragma unroll
  for (int off = 16; off <= 32; off <<= 1) {
    int v0 = __shfl_xor(*(int*)&A0, off);
    int v1 = __shfl_xor(*(int*)&A1, off);
    int v2 = __shfl_xor(*(int*)&A2, off);
    int v3 = __shfl_xor(*(int*)&A3, off);
    A0 = __hadd2(A0, *(__half2*)&v0);
    A1 = __hadd2(A1, *(__half2*)&v1);
    A2 = __hadd2(A2, *(__half2*)&v2);
    A3 = __hadd2(A3, *(__half2*)&v3);
  }
  if (quarter == 0) {
    float2 f0 = __half22float2(A0), f1 = __half22float2(A1);
    float2 f2 = __half22float2(A2), f3 = __half22float2(A3);
    ushort4 h0, h1;
    h0.x = f2bf(f0.x * inv); h0.y = f2bf(f0.y * inv);
    h0.z = f2bf(f1.x * inv); h0.w = f2bf(f1.y * inv);
    h1.x = f2bf(f2.x * inv); h1.y = f2bf(f2.y * inv);
    h1.z = f2bf(f3.x * inv); h1.w = f2bf(f3.y * inv);
    size_t oidx = ((size_t)(b * S_ + i)) * HD_ + h * DH_ + d0;
    *(ushort4*)(oh + oidx) = h0;
    *(ushort4*)(oh + oidx + 4) = h1;
  }
}

extern "C" void kernel_launch(void* const* d_in, const int* in_sizes, int n_in,
                              void* d_out, int out_size, void* d_ws, size_t ws_size,
                              hipStream_t stream) {
  (void)in_sizes; (void)n_in; (void)out_size; (void)ws_size;
  const float* x  = (const float*)d_in[0];
  const float* Wq = (const float*)d_in[1];
  const float* Wc = (const float*)d_in[2];
  const float* Wk = (const float*)d_in[3];
  const float* Wv = (const float*)d_in[4];
  const float* Wo = (const float*)d_in[5];
  const int* forget = (const int*)d_in[6];  // bool widened to int32 (verified r3)

  char* ws = (char*)d_ws;
  size_t off = 0;
  auto alloc = [&](size_t bytes) { char* p = ws + off; off += (bytes + 255) & ~(size_t)255; return p; };

  unsigned short* x_bf = (unsigned short*)alloc((size_t)4096 * 2048 * 2);  // reused as o
  unsigned short* WqT  = (unsigned short*)alloc((size_t)2048 * 2048 * 2);
  unsigned short* WcTh = (unsigned short*)alloc((size_t)512 * 2048 * 2);
  unsigned short* WcTl = (unsigned short*)alloc((size_t)512 * 2048 * 2);
  unsigned short* WkT  = (unsigned short*)alloc((size_t)2048 * 512 * 2);
  unsigned short* WvT  = (unsigned short*)alloc((size_t)2048 * 512 * 2);
  unsigned short* WoT  = (unsigned short*)alloc((size_t)2048 * 2048 * 2);
  unsigned short* q_hi = (unsigned short*)alloc((size_t)4096 * 2048 * 2);
  unsigned short* c_hi = (unsigned short*)alloc((size_t)4096 * 512 * 2);
  unsigned short* k_hi = (unsigned short*)alloc((size_t)4096 * 2048 * 2);
  unsigned short* v_hf = (unsigned short*)alloc((size_t)4096 * 2048 * 2);

  unsigned short* o_hi = x_bf;

  const float scale = 0.08838834764831845f;

  prep_all<<<13312, 256, 0, stream>>>(x, Wq, Wc, Wk, Wv, Wo,
                                      x_bf, WqT, WcTh, WcTl, WkT, WvT, WoT);

  gemm_c64<<<dim3(64, 4), 256, 0, stream>>>(x_bf, WcTh, WcTl, c_hi, 4096, 512, 2048);
  gemm_1term<<<dim3(32, 16), 256, 0, stream>>>(x_bf, WqT, q_hi, 4096, 2048, 2048, scale);
  gemm_1term<<<dim3(32, 16), 256, 0, stream>>>(c_hi, WkT, k_hi, 4096, 2048, 512, 1.0f);
  gemm_1h<<<dim3(32, 16), 256, 0, stream>>>(c_hi, WvT, v_hf, 4096, 2048, 512);

  attn_fused<<<4096, 1024, 0, stream>>>(q_hi, k_hi, v_hf, forget, o_hi);

  gemm_1f<<<dim3(32, 16), 256, 0, stream>>>(o_hi, WoT, (float*)d_out, 4096, 2048, 2048);
}